// Round 1
// baseline (1034.587 us; speedup 1.0000x reference)
//
#include <hip/hip_runtime.h>
#include <stdint.h>

#define NBOX 2000000
#define NCLS 10
#define KPRE 4096
#define KPOST 500
#define CAND_CAP 262144

// ---- workspace layout (bytes) ----
#define OFF_KEYS   ((size_t)0)
#define OFF_CAND   ((size_t)16000000)                       // NBOX*8
#define OFF_CAND2  (OFF_CAND  + (size_t)CAND_CAP * 8)       // 18,097,152
#define OFF_SEL    (OFF_CAND2 + (size_t)KPRE * 8)
#define OFF_SKEYS  (OFF_SEL   + (size_t)KPRE * 8)
#define OFF_SUP    (OFF_SKEYS + (size_t)KPRE * 8)
#define OFF_VMASK  (OFF_SUP   + (size_t)KPRE * 64 * 8)      // 2 MB sup matrix
#define OFF_HIST   (OFF_VMASK + (size_t)64 * 8)
#define OFF_STATE  (OFF_HIST  + (size_t)768 * 4)
#define OFF_ARR    (OFF_STATE + (size_t)64)
// x1a,y1a,x2a,y2a,vala : float[4096] each, laba : int[4096]

struct NmsState {
  uint32_t b1, b2, b3;
  uint32_t need1, need2, need3;
  uint32_t cand_cnt, cand2_cnt, sel_cnt;
  uint32_t pad;
  unsigned long long pivot;
};

// monotone float->uint mapping: larger float -> larger ord
__device__ __forceinline__ uint32_t f2ord(float f) {
  uint32_t b = __float_as_uint(f);
  return (b & 0x80000000u) ? ~b : (b | 0x80000000u);
}
__device__ __forceinline__ float ord2f(uint32_t ord) {
  uint32_t b = (ord & 0x80000000u) ? (ord ^ 0x80000000u) : ~ord;
  return __uint_as_float(b);
}

// wave-aggregated LDS histogram add (distinct-bin loop; typically 1-3 iters)
__device__ __forceinline__ void hist_add_wave(uint32_t* lh, uint32_t bin) {
  unsigned long long act = __ballot(1);
  int lane = threadIdx.x & 63;
  unsigned long long rem = act;
  while (rem) {
    int leader = __builtin_ctzll(rem);
    uint32_t lb = __shfl(bin, leader);
    unsigned long long same = __ballot(bin == lb) & act;
    if (lane == leader) atomicAdd(&lh[lb], (uint32_t)__builtin_popcountll(same));
    rem &= ~same;
  }
}

// wave-aggregated compaction: one atomic per wave
__device__ __forceinline__ void wave_compact(bool take, unsigned long long key,
                                             uint32_t* counter, unsigned long long* buf,
                                             uint32_t cap) {
  unsigned long long mm = __ballot(take);
  if (take) {
    int lane = threadIdx.x & 63;
    unsigned long long lt = (lane == 0) ? 0ull : (~0ull >> (64 - lane));
    int rank = __builtin_popcountll(mm & lt);
    int leader = __builtin_ctzll(mm);
    uint32_t base = 0;
    if (rank == 0) base = atomicAdd(counter, (uint32_t)__builtin_popcountll(mm));
    base = __shfl(base, leader);
    uint32_t pos = base + (uint32_t)rank;
    if (pos < cap) buf[pos] = key;
  }
}

// ---------------- kernels ----------------

__global__ void k_zero(uint32_t* hist, NmsState* st, unsigned long long* vmask) {
  int t = threadIdx.x;
  for (int i = t; i < 768; i += blockDim.x) hist[i] = 0;
  if (t < 64) vmask[t] = 0;
  if (t == 0) *st = NmsState{};
}

// scores (max over classes), masked, 64-bit keys, byte0 histogram
__global__ void k_score(const float* __restrict__ cls, unsigned long long* __restrict__ keys,
                        uint32_t* __restrict__ hist0) {
  __shared__ uint32_t lh[256];
  for (int i = threadIdx.x; i < 256; i += blockDim.x) lh[i] = 0;
  __syncthreads();
  const int nvec = NBOX / 4;
  for (int v = blockIdx.x * blockDim.x + threadIdx.x; v < nvec; v += gridDim.x * blockDim.x) {
    float4 m = reinterpret_cast<const float4*>(cls)[v];
    #pragma unroll
    for (int c = 1; c < NCLS; ++c) {
      float4 x = reinterpret_cast<const float4*>(cls + (size_t)c * NBOX)[v];
      m.x = fmaxf(m.x, x.x); m.y = fmaxf(m.y, x.y);
      m.z = fmaxf(m.z, x.z); m.w = fmaxf(m.w, x.w);
    }
    float s[4] = {m.x, m.y, m.z, m.w};
    #pragma unroll
    for (int q = 0; q < 4; ++q) {
      float ms = (s[q] >= 0.1f) ? s[q] : -1.0f;
      uint32_t u = ~f2ord(ms);
      keys[4 * v + q] = ((unsigned long long)u << 32) | (uint32_t)(4 * v + q);
      hist_add_wave(lh, u >> 24);
    }
  }
  __syncthreads();
  for (int i = threadIdx.x; i < 256; i += blockDim.x)
    if (lh[i]) atomicAdd(&hist0[i], lh[i]);
}

// scan a 256-bin histogram for the bucket containing the need-th smallest
__global__ void k_scan(const uint32_t* __restrict__ hist, NmsState* st, int stage) {
  if (threadIdx.x != 0 || blockIdx.x != 0) return;
  uint32_t need = (stage == 0) ? (uint32_t)KPRE : (stage == 1 ? st->need1 : st->need2);
  uint32_t cum = 0, b = 255;
  for (int i = 0; i < 256; ++i) {
    uint32_t c = hist[i];
    if (cum + c >= need) { b = (uint32_t)i; break; }
    cum += c;
  }
  uint32_t nd = need - cum;
  if (stage == 0)      { st->b1 = b; st->need1 = nd; }
  else if (stage == 1) { st->b2 = b; st->need2 = nd; }
  else                 { st->b3 = b; st->need3 = nd; }
}

// byte1 histogram among byte0==b1
__global__ void k_hist1(const unsigned long long* __restrict__ keys,
                        const NmsState* __restrict__ st, uint32_t* __restrict__ hist1) {
  __shared__ uint32_t lh[256];
  for (int i = threadIdx.x; i < 256; i += blockDim.x) lh[i] = 0;
  __syncthreads();
  uint32_t b1 = st->b1;
  for (int i = blockIdx.x * blockDim.x + threadIdx.x; i < NBOX; i += gridDim.x * blockDim.x) {
    uint32_t u = (uint32_t)(keys[i] >> 32);
    if ((u >> 24) == b1) hist_add_wave(lh, (u >> 16) & 0xffu);
  }
  __syncthreads();
  for (int i = threadIdx.x; i < 256; i += blockDim.x)
    if (lh[i]) atomicAdd(&hist1[i], lh[i]);
}

// compact all keys with top16 <= (b1,b2); histogram byte2 among top16 == (b1,b2)
__global__ void k_compact_hist2(const unsigned long long* __restrict__ keys,
                                NmsState* st, uint32_t* __restrict__ hist2,
                                unsigned long long* __restrict__ cand) {
  __shared__ uint32_t lh[256];
  for (int i = threadIdx.x; i < 256; i += blockDim.x) lh[i] = 0;
  __syncthreads();
  uint32_t p16 = (st->b1 << 8) | st->b2;
  for (int i = blockIdx.x * blockDim.x + threadIdx.x; i < NBOX; i += gridDim.x * blockDim.x) {
    unsigned long long key = keys[i];
    uint32_t u = (uint32_t)(key >> 32);
    uint32_t pref = u >> 16;
    bool take = (pref <= p16);
    wave_compact(take, key, &st->cand_cnt, cand, CAND_CAP);
    if (take && pref == p16) hist_add_wave(lh, (u >> 8) & 0xffu);
  }
  __syncthreads();
  for (int i = threadIdx.x; i < 256; i += blockDim.x)
    if (lh[i]) atomicAdd(&hist2[i], lh[i]);
}

// filter candidates with top24 == (b1,b2,b3) into cand2
__global__ void k_filter24(const unsigned long long* __restrict__ cand, NmsState* st,
                           unsigned long long* __restrict__ cand2) {
  uint32_t n = min(st->cand_cnt, (uint32_t)CAND_CAP);
  uint32_t p24 = (st->b1 << 16) | (st->b2 << 8) | st->b3;
  for (uint32_t i = blockIdx.x * blockDim.x + threadIdx.x; i < n; i += gridDim.x * blockDim.x) {
    unsigned long long key = cand[i];
    uint32_t u = (uint32_t)(key >> 32);
    bool take = ((u >> 8) == p24);
    wave_compact(take, key, &st->cand2_cnt, cand2, (uint32_t)KPRE);
  }
}

__device__ void bitonic4096(unsigned long long* s) {
  for (int k = 2; k <= KPRE; k <<= 1)
    for (int j = k >> 1; j > 0; j >>= 1) {
      __syncthreads();
      for (int t = threadIdx.x; t < KPRE; t += blockDim.x) {
        int ixj = t ^ j;
        if (ixj > t) {
          bool up = ((t & k) == 0);
          unsigned long long a = s[t], b = s[ixj];
          if ((a > b) == up) { s[t] = b; s[ixj] = a; }
        }
      }
    }
  __syncthreads();
}

// sort pivot bucket, pivot = need3-th smallest
__global__ void k_pivot(const unsigned long long* __restrict__ cand2, NmsState* st) {
  __shared__ unsigned long long s[KPRE];
  uint32_t n = min(st->cand2_cnt, (uint32_t)KPRE);
  for (int t = threadIdx.x; t < KPRE; t += blockDim.x)
    s[t] = (t < (int)n) ? cand2[t] : ~0ull;
  bitonic4096(s);
  if (threadIdx.x == 0) {
    uint32_t nd = st->need3;
    st->pivot = s[nd - 1];
  }
}

// select all keys <= pivot from cand (exactly 4096)
__global__ void k_select(const unsigned long long* __restrict__ cand, NmsState* st,
                         unsigned long long* __restrict__ sel) {
  uint32_t n = min(st->cand_cnt, (uint32_t)CAND_CAP);
  unsigned long long piv = st->pivot;
  for (uint32_t i = blockIdx.x * blockDim.x + threadIdx.x; i < n; i += gridDim.x * blockDim.x) {
    unsigned long long key = cand[i];
    wave_compact(key <= piv, key, &st->sel_cnt, sel, (uint32_t)KPRE);
  }
}

// sort the selected 4096 into final (score desc, idx asc) order
__global__ void k_sortsel(const unsigned long long* __restrict__ sel, const NmsState* st,
                          unsigned long long* __restrict__ skeys) {
  __shared__ unsigned long long s[KPRE];
  uint32_t n = min(st->sel_cnt, (uint32_t)KPRE);
  for (int t = threadIdx.x; t < KPRE; t += blockDim.x)
    s[t] = (t < (int)n) ? sel[t] : ~0ull;
  bitonic4096(s);
  for (int t = threadIdx.x; t < KPRE; t += blockDim.x) skeys[t] = s[t];
}

// gather boxes / labels / values for the sorted 4096
__global__ void k_gather(const unsigned long long* __restrict__ skeys,
                         const float* __restrict__ boxes, const float* __restrict__ cls,
                         float* __restrict__ x1a, float* __restrict__ y1a,
                         float* __restrict__ x2a, float* __restrict__ y2a,
                         float* __restrict__ vala, int* __restrict__ laba,
                         unsigned long long* __restrict__ vmask) {
  int t = blockIdx.x * blockDim.x + threadIdx.x;
  if (t >= KPRE) return;
  unsigned long long key = skeys[t];
  uint32_t idx = (uint32_t)key;
  if (idx >= NBOX) idx = 0;  // safety (only on pipeline failure)
  uint32_t u = (uint32_t)(key >> 32);
  float val = ord2f(~u);
  x1a[t] = boxes[idx];
  y1a[t] = boxes[(size_t)NBOX + idx];
  x2a[t] = boxes[(size_t)2 * NBOX + idx];
  y2a[t] = boxes[(size_t)3 * NBOX + idx];
  float best = cls[idx];
  int lab = 0;
  #pragma unroll
  for (int c = 1; c < NCLS; ++c) {
    float v = cls[(size_t)c * NBOX + idx];
    if (v > best) { best = v; lab = c; }
  }
  vala[t] = val;
  laba[t] = lab;
  if (val >= 0.1f) atomicOr(&vmask[t >> 6], 1ull << (t & 63));
}

// 4096x4096 suppression bit-matrix; row i word bx: bits for j in [bx*64, bx*64+63], j>i, iou>0.5
__global__ void k_supmat(const float* __restrict__ x1a, const float* __restrict__ y1a,
                         const float* __restrict__ x2a, const float* __restrict__ y2a,
                         unsigned long long* __restrict__ sup) {
#pragma clang fp contract(off)
  int bx = blockIdx.x, by = blockIdx.y;
  int t = threadIdx.x;  // 64 threads
  int i = by * 64 + t;
  if (bx < by) { sup[(size_t)i * 64 + bx] = 0ull; return; }
  __shared__ float sx1[64], sy1[64], sx2[64], sy2[64], sar[64];
  int j0 = bx * 64 + t;
  float cx1 = x1a[j0], cy1 = y1a[j0], cx2 = x2a[j0], cy2 = y2a[j0];
  sx1[t] = cx1; sy1[t] = cy1; sx2[t] = cx2; sy2[t] = cy2;
  sar[t] = fmaxf(cx2 - cx1, 0.0f) * fmaxf(cy2 - cy1, 0.0f);
  __syncthreads();
  float x1i = x1a[i], y1i = y1a[i], x2i = x2a[i], y2i = y2a[i];
  float ari = fmaxf(x2i - x1i, 0.0f) * fmaxf(y2i - y1i, 0.0f);
  unsigned long long w = 0ull;
  #pragma unroll 8
  for (int jj = 0; jj < 64; ++jj) {
    int j = bx * 64 + jj;
    float iw = fmaxf(fminf(x2i, sx2[jj]) - fmaxf(x1i, sx1[jj]), 0.0f);
    float ih = fmaxf(fminf(y2i, sy2[jj]) - fmaxf(y1i, sy1[jj]), 0.0f);
    float inter = iw * ih;
    float den = ((ari + sar[jj]) - inter) + 1e-8f;  // exact ref op order
    float iou = inter / den;
    if ((iou > 0.5f) && (j > i)) w |= (1ull << jj);
  }
  sup[(size_t)i * 64 + bx] = w;
}

// single-wave sequential greedy scan + output write
__global__ void k_scan_nms(const unsigned long long* __restrict__ sup,
                           const unsigned long long* __restrict__ vmask,
                           const float* __restrict__ x1a, const float* __restrict__ y1a,
                           const float* __restrict__ x2a, const float* __restrict__ y2a,
                           const float* __restrict__ vala, const int* __restrict__ laba,
                           float* __restrict__ out) {
  int lane = threadIdx.x;  // 64 threads = 1 wave
  unsigned long long keep = vmask[lane];

  // zero the output (harness poisons it)
  for (int t = lane; t < KPOST * 6; t += 64) out[t] = 0.0f;

  const int D = 32;
  unsigned long long pre[D];
  #pragma unroll
  for (int d = 0; d < D; ++d) pre[d] = sup[(size_t)d * 64 + lane];

  for (int base = 0; base < KPRE; base += D) {
    #pragma unroll
    for (int d = 0; d < D; ++d) {
      int i = base + d;
      unsigned long long row = pre[d];
      int nf = base + D + d;
      pre[d] = (nf < KPRE) ? sup[(size_t)nf * 64 + lane] : 0ull;
      unsigned long long kw = __shfl(keep, i >> 6);
      if ((kw >> (i & 63)) & 1ull) keep &= ~row;
    }
  }

  // ranks: exclusive prefix of popcounts across lanes
  int cnt = __builtin_popcountll(keep);
  int pfx = 0;
  for (int l = 0; l < 64; ++l) {
    int c = __shfl(cnt, l);
    if (l < lane) pfx += c;
  }
  __syncthreads();  // order zero-fill before row writes

  unsigned long long kk = keep;
  int local = 0;
  while (kk) {
    int b = __builtin_ctzll(kk);
    kk &= kk - 1;
    int rank = pfx + local; local++;
    if (rank < KPOST) {
      int i = lane * 64 + b;
      out[rank * 6 + 0] = x1a[i];
      out[rank * 6 + 1] = y1a[i];
      out[rank * 6 + 2] = x2a[i];
      out[rank * 6 + 3] = y2a[i];
      out[rank * 6 + 4] = vala[i];
      out[rank * 6 + 5] = (float)laba[i];
    }
  }
}

extern "C" void kernel_launch(void* const* d_in, const int* in_sizes, int n_in,
                              void* d_out, int out_size, void* d_ws, size_t ws_size,
                              hipStream_t stream) {
  const float* boxes = (const float*)d_in[0];
  const float* cls   = (const float*)d_in[1];
  float* out = (float*)d_out;
  char* ws = (char*)d_ws;

  unsigned long long* keys  = (unsigned long long*)(ws + OFF_KEYS);
  unsigned long long* cand  = (unsigned long long*)(ws + OFF_CAND);
  unsigned long long* cand2 = (unsigned long long*)(ws + OFF_CAND2);
  unsigned long long* sel   = (unsigned long long*)(ws + OFF_SEL);
  unsigned long long* skeys = (unsigned long long*)(ws + OFF_SKEYS);
  unsigned long long* sup   = (unsigned long long*)(ws + OFF_SUP);
  unsigned long long* vmask = (unsigned long long*)(ws + OFF_VMASK);
  uint32_t* hist = (uint32_t*)(ws + OFF_HIST);
  NmsState* st = (NmsState*)(ws + OFF_STATE);
  float* x1a = (float*)(ws + OFF_ARR);
  float* y1a = x1a + KPRE;
  float* x2a = y1a + KPRE;
  float* y2a = x2a + KPRE;
  float* vala = y2a + KPRE;
  int*   laba = (int*)(vala + KPRE);

  k_zero<<<1, 256, 0, stream>>>(hist, st, vmask);
  k_score<<<1024, 256, 0, stream>>>(cls, keys, hist);
  k_scan<<<1, 64, 0, stream>>>(hist, st, 0);
  k_hist1<<<1024, 256, 0, stream>>>(keys, st, hist + 256);
  k_scan<<<1, 64, 0, stream>>>(hist + 256, st, 1);
  k_compact_hist2<<<1024, 256, 0, stream>>>(keys, st, hist + 512, cand);
  k_scan<<<1, 64, 0, stream>>>(hist + 512, st, 2);
  k_filter24<<<64, 256, 0, stream>>>(cand, st, cand2);
  k_pivot<<<1, 1024, 0, stream>>>(cand2, st);
  k_select<<<64, 256, 0, stream>>>(cand, st, sel);
  k_sortsel<<<1, 1024, 0, stream>>>(sel, st, skeys);
  k_gather<<<16, 256, 0, stream>>>(skeys, boxes, cls, x1a, y1a, x2a, y2a, vala, laba, vmask);
  k_supmat<<<dim3(64, 64), 64, 0, stream>>>(x1a, y1a, x2a, y2a, sup);
  k_scan_nms<<<1, 64, 0, stream>>>(sup, vmask, x1a, y1a, x2a, y2a, vala, laba, out);
}

// Round 2
// 918.159 us; speedup vs baseline: 1.1268x; 1.1268x over previous
//
#include <hip/hip_runtime.h>
#include <stdint.h>

#define NBOX 2000000
#define NCLS 10
#define KPRE 4096
#define KPOST 500
#define CAND_CAP 262144

// ---- workspace layout (bytes) ----
#define OFF_KEYS   ((size_t)0)
#define OFF_CAND   ((size_t)16000000)                       // NBOX*8
#define OFF_CAND2  (OFF_CAND  + (size_t)CAND_CAP * 8)
#define OFF_SEL    (OFF_CAND2 + (size_t)KPRE * 8)
#define OFF_SKEYS  (OFF_SEL   + (size_t)KPRE * 8)
#define OFF_SUP    (OFF_SKEYS + (size_t)KPRE * 8)
#define OFF_VMASK  (OFF_SUP   + (size_t)KPRE * 64 * 8)      // 2 MB sup matrix
#define OFF_HIST   (OFF_VMASK + (size_t)64 * 8)
#define OFF_STATE  (OFF_HIST  + (size_t)768 * 4)
#define OFF_ARR    (OFF_STATE + (size_t)64)
#define OFF_DIAG   (OFF_ARR   + (size_t)KPRE * 24)          // 4096 u64 diagonal words

struct NmsState {
  uint32_t b1, b2, b3;
  uint32_t need1, need2, need3;
  uint32_t cand_cnt, cand2_cnt, sel_cnt;
  uint32_t pad;
  unsigned long long pivot;
};

// monotone float->uint mapping: larger float -> larger ord
__device__ __forceinline__ uint32_t f2ord(float f) {
  uint32_t b = __float_as_uint(f);
  return (b & 0x80000000u) ? ~b : (b | 0x80000000u);
}
__device__ __forceinline__ float ord2f(uint32_t ord) {
  uint32_t b = (ord & 0x80000000u) ? (ord ^ 0x80000000u) : ~ord;
  return __uint_as_float(b);
}

__device__ __forceinline__ unsigned long long readlane64(unsigned long long v, int l) {
  uint32_t lo = (uint32_t)__builtin_amdgcn_readlane((int)(uint32_t)v, l);
  uint32_t hi = (uint32_t)__builtin_amdgcn_readlane((int)(uint32_t)(v >> 32), l);
  return ((unsigned long long)hi << 32) | lo;
}

// wave-aggregated LDS histogram add (distinct-bin loop; typically 1-3 iters)
__device__ __forceinline__ void hist_add_wave(uint32_t* lh, uint32_t bin) {
  unsigned long long act = __ballot(1);
  int lane = threadIdx.x & 63;
  unsigned long long rem = act;
  while (rem) {
    int leader = __builtin_ctzll(rem);
    uint32_t lb = __shfl(bin, leader);
    unsigned long long same = __ballot(bin == lb) & act;
    if (lane == leader) atomicAdd(&lh[lb], (uint32_t)__builtin_popcountll(same));
    rem &= ~same;
  }
}

// wave-aggregated compaction: one atomic per wave
__device__ __forceinline__ void wave_compact(bool take, unsigned long long key,
                                             uint32_t* counter, unsigned long long* buf,
                                             uint32_t cap) {
  unsigned long long mm = __ballot(take);
  if (take) {
    int lane = threadIdx.x & 63;
    unsigned long long lt = (lane == 0) ? 0ull : (~0ull >> (64 - lane));
    int rank = __builtin_popcountll(mm & lt);
    int leader = __builtin_ctzll(mm);
    uint32_t base = 0;
    if (rank == 0) base = atomicAdd(counter, (uint32_t)__builtin_popcountll(mm));
    base = __shfl(base, leader);
    uint32_t pos = base + (uint32_t)rank;
    if (pos < cap) buf[pos] = key;
  }
}

// ---------------- kernels ----------------

__global__ void k_zero(uint32_t* hist, NmsState* st, unsigned long long* vmask) {
  int t = threadIdx.x;
  for (int i = t; i < 768; i += blockDim.x) hist[i] = 0;
  if (t < 64) vmask[t] = 0;
  if (t == 0) *st = NmsState{};
}

// scores (max over classes), masked, 64-bit keys, byte0 histogram
__global__ void k_score(const float* __restrict__ cls, unsigned long long* __restrict__ keys,
                        uint32_t* __restrict__ hist0) {
  __shared__ uint32_t lh[256];
  for (int i = threadIdx.x; i < 256; i += blockDim.x) lh[i] = 0;
  __syncthreads();
  const int nvec = NBOX / 4;
  for (int v = blockIdx.x * blockDim.x + threadIdx.x; v < nvec; v += gridDim.x * blockDim.x) {
    float4 m = reinterpret_cast<const float4*>(cls)[v];
    #pragma unroll
    for (int c = 1; c < NCLS; ++c) {
      float4 x = reinterpret_cast<const float4*>(cls + (size_t)c * NBOX)[v];
      m.x = fmaxf(m.x, x.x); m.y = fmaxf(m.y, x.y);
      m.z = fmaxf(m.z, x.z); m.w = fmaxf(m.w, x.w);
    }
    float s[4] = {m.x, m.y, m.z, m.w};
    #pragma unroll
    for (int q = 0; q < 4; ++q) {
      float ms = (s[q] >= 0.1f) ? s[q] : -1.0f;
      uint32_t u = ~f2ord(ms);
      keys[4 * v + q] = ((unsigned long long)u << 32) | (uint32_t)(4 * v + q);
      hist_add_wave(lh, u >> 24);
    }
  }
  __syncthreads();
  for (int i = threadIdx.x; i < 256; i += blockDim.x)
    if (lh[i]) atomicAdd(&hist0[i], lh[i]);
}

// scan a 256-bin histogram for the bucket containing the need-th smallest
__global__ void k_scan(const uint32_t* __restrict__ hist, NmsState* st, int stage) {
  if (threadIdx.x != 0 || blockIdx.x != 0) return;
  uint32_t need = (stage == 0) ? (uint32_t)KPRE : (stage == 1 ? st->need1 : st->need2);
  uint32_t cum = 0, b = 255;
  for (int i = 0; i < 256; ++i) {
    uint32_t c = hist[i];
    if (cum + c >= need) { b = (uint32_t)i; break; }
    cum += c;
  }
  uint32_t nd = need - cum;
  if (stage == 0)      { st->b1 = b; st->need1 = nd; }
  else if (stage == 1) { st->b2 = b; st->need2 = nd; }
  else                 { st->b3 = b; st->need3 = nd; }
}

// byte1 histogram among byte0==b1
__global__ void k_hist1(const unsigned long long* __restrict__ keys,
                        const NmsState* __restrict__ st, uint32_t* __restrict__ hist1) {
  __shared__ uint32_t lh[256];
  for (int i = threadIdx.x; i < 256; i += blockDim.x) lh[i] = 0;
  __syncthreads();
  uint32_t b1 = st->b1;
  for (int i = blockIdx.x * blockDim.x + threadIdx.x; i < NBOX; i += gridDim.x * blockDim.x) {
    uint32_t u = (uint32_t)(keys[i] >> 32);
    if ((u >> 24) == b1) hist_add_wave(lh, (u >> 16) & 0xffu);
  }
  __syncthreads();
  for (int i = threadIdx.x; i < 256; i += blockDim.x)
    if (lh[i]) atomicAdd(&hist1[i], lh[i]);
}

// compact all keys with top16 <= (b1,b2); histogram byte2 among top16 == (b1,b2)
__global__ void k_compact_hist2(const unsigned long long* __restrict__ keys,
                                NmsState* st, uint32_t* __restrict__ hist2,
                                unsigned long long* __restrict__ cand) {
  __shared__ uint32_t lh[256];
  for (int i = threadIdx.x; i < 256; i += blockDim.x) lh[i] = 0;
  __syncthreads();
  uint32_t p16 = (st->b1 << 8) | st->b2;
  for (int i = blockIdx.x * blockDim.x + threadIdx.x; i < NBOX; i += gridDim.x * blockDim.x) {
    unsigned long long key = keys[i];
    uint32_t u = (uint32_t)(key >> 32);
    uint32_t pref = u >> 16;
    bool take = (pref <= p16);
    wave_compact(take, key, &st->cand_cnt, cand, CAND_CAP);
    if (take && pref == p16) hist_add_wave(lh, (u >> 8) & 0xffu);
  }
  __syncthreads();
  for (int i = threadIdx.x; i < 256; i += blockDim.x)
    if (lh[i]) atomicAdd(&hist2[i], lh[i]);
}

// filter candidates with top24 == (b1,b2,b3) into cand2
__global__ void k_filter24(const unsigned long long* __restrict__ cand, NmsState* st,
                           unsigned long long* __restrict__ cand2) {
  uint32_t n = min(st->cand_cnt, (uint32_t)CAND_CAP);
  uint32_t p24 = (st->b1 << 16) | (st->b2 << 8) | st->b3;
  for (uint32_t i = blockIdx.x * blockDim.x + threadIdx.x; i < n; i += gridDim.x * blockDim.x) {
    unsigned long long key = cand[i];
    uint32_t u = (uint32_t)(key >> 32);
    bool take = ((u >> 8) == p24);
    wave_compact(take, key, &st->cand2_cnt, cand2, (uint32_t)KPRE);
  }
}

__device__ void bitonic4096(unsigned long long* s) {
  for (int k = 2; k <= KPRE; k <<= 1)
    for (int j = k >> 1; j > 0; j >>= 1) {
      __syncthreads();
      for (int t = threadIdx.x; t < KPRE; t += blockDim.x) {
        int ixj = t ^ j;
        if (ixj > t) {
          bool up = ((t & k) == 0);
          unsigned long long a = s[t], b = s[ixj];
          if ((a > b) == up) { s[t] = b; s[ixj] = a; }
        }
      }
    }
  __syncthreads();
}

// sort pivot bucket, pivot = need3-th smallest
__global__ void k_pivot(const unsigned long long* __restrict__ cand2, NmsState* st) {
  __shared__ unsigned long long s[KPRE];
  uint32_t n = min(st->cand2_cnt, (uint32_t)KPRE);
  for (int t = threadIdx.x; t < KPRE; t += blockDim.x)
    s[t] = (t < (int)n) ? cand2[t] : ~0ull;
  bitonic4096(s);
  if (threadIdx.x == 0) {
    uint32_t nd = st->need3;
    st->pivot = s[nd - 1];
  }
}

// select all keys <= pivot from cand (exactly 4096)
__global__ void k_select(const unsigned long long* __restrict__ cand, NmsState* st,
                         unsigned long long* __restrict__ sel) {
  uint32_t n = min(st->cand_cnt, (uint32_t)CAND_CAP);
  unsigned long long piv = st->pivot;
  for (uint32_t i = blockIdx.x * blockDim.x + threadIdx.x; i < n; i += gridDim.x * blockDim.x) {
    unsigned long long key = cand[i];
    wave_compact(key <= piv, key, &st->sel_cnt, sel, (uint32_t)KPRE);
  }
}

// sort the selected 4096 into final (score desc, idx asc) order
__global__ void k_sortsel(const unsigned long long* __restrict__ sel, const NmsState* st,
                          unsigned long long* __restrict__ skeys) {
  __shared__ unsigned long long s[KPRE];
  uint32_t n = min(st->sel_cnt, (uint32_t)KPRE);
  for (int t = threadIdx.x; t < KPRE; t += blockDim.x)
    s[t] = (t < (int)n) ? sel[t] : ~0ull;
  bitonic4096(s);
  for (int t = threadIdx.x; t < KPRE; t += blockDim.x) skeys[t] = s[t];
}

// gather boxes / labels / values for the sorted 4096
__global__ void k_gather(const unsigned long long* __restrict__ skeys,
                         const float* __restrict__ boxes, const float* __restrict__ cls,
                         float* __restrict__ x1a, float* __restrict__ y1a,
                         float* __restrict__ x2a, float* __restrict__ y2a,
                         float* __restrict__ vala, int* __restrict__ laba,
                         unsigned long long* __restrict__ vmask) {
  int t = blockIdx.x * blockDim.x + threadIdx.x;
  if (t >= KPRE) return;
  unsigned long long key = skeys[t];
  uint32_t idx = (uint32_t)key;
  if (idx >= NBOX) idx = 0;  // safety (only on pipeline failure)
  uint32_t u = (uint32_t)(key >> 32);
  float val = ord2f(~u);
  x1a[t] = boxes[idx];
  y1a[t] = boxes[(size_t)NBOX + idx];
  x2a[t] = boxes[(size_t)2 * NBOX + idx];
  y2a[t] = boxes[(size_t)3 * NBOX + idx];
  float best = cls[idx];
  int lab = 0;
  #pragma unroll
  for (int c = 1; c < NCLS; ++c) {
    float v = cls[(size_t)c * NBOX + idx];
    if (v > best) { best = v; lab = c; }
  }
  vala[t] = val;
  laba[t] = lab;
  if (val >= 0.1f) atomicOr(&vmask[t >> 6], 1ull << (t & 63));
}

// 4096x4096 suppression bit-matrix; row i word bx: bits for j in [bx*64, bx*64+63], j>i, iou>0.5
// Also writes the diagonal block word (bx==by) to dg[i].
__global__ void k_supmat(const float* __restrict__ x1a, const float* __restrict__ y1a,
                         const float* __restrict__ x2a, const float* __restrict__ y2a,
                         unsigned long long* __restrict__ sup,
                         unsigned long long* __restrict__ dg) {
#pragma clang fp contract(off)
  int bx = blockIdx.x, by = blockIdx.y;
  int t = threadIdx.x;  // 64 threads
  int i = by * 64 + t;
  if (bx < by) { sup[(size_t)i * 64 + bx] = 0ull; return; }
  __shared__ float sx1[64], sy1[64], sx2[64], sy2[64], sar[64];
  int j0 = bx * 64 + t;
  float cx1 = x1a[j0], cy1 = y1a[j0], cx2 = x2a[j0], cy2 = y2a[j0];
  sx1[t] = cx1; sy1[t] = cy1; sx2[t] = cx2; sy2[t] = cy2;
  sar[t] = fmaxf(cx2 - cx1, 0.0f) * fmaxf(cy2 - cy1, 0.0f);
  __syncthreads();
  float x1i = x1a[i], y1i = y1a[i], x2i = x2a[i], y2i = y2a[i];
  float ari = fmaxf(x2i - x1i, 0.0f) * fmaxf(y2i - y1i, 0.0f);
  unsigned long long w = 0ull;
  #pragma unroll 8
  for (int jj = 0; jj < 64; ++jj) {
    int j = bx * 64 + jj;
    float iw = fmaxf(fminf(x2i, sx2[jj]) - fmaxf(x1i, sx1[jj]), 0.0f);
    float ih = fmaxf(fminf(y2i, sy2[jj]) - fmaxf(y1i, sy1[jj]), 0.0f);
    float inter = iw * ih;
    float den = ((ari + sar[jj]) - inter) + 1e-8f;  // exact ref op order
    float iou = inter / den;
    if ((iou > 0.5f) && (j > i)) w |= (1ull << jj);
  }
  sup[(size_t)i * 64 + bx] = w;
  if (bx == by) dg[i] = w;
}

// single-wave greedy scan, block-resolved: serial work only on nonzero diagonal rows
__global__ void k_scan_nms(const unsigned long long* __restrict__ sup,
                           const unsigned long long* __restrict__ diag,
                           const unsigned long long* __restrict__ vmask,
                           const float* __restrict__ x1a, const float* __restrict__ y1a,
                           const float* __restrict__ x2a, const float* __restrict__ y2a,
                           const float* __restrict__ vala, const int* __restrict__ laba,
                           float* __restrict__ out) {
  int lane = threadIdx.x;  // 64 threads = 1 wave
  unsigned long long keep = vmask[lane];

  // zero the output (harness poisons it)
  for (int t = lane; t < KPOST * 6; t += 64) out[t] = 0.0f;

  // double-buffered 16-row chunks; chunk c covers rows [c*16, c*16+16)
  unsigned long long A[16], B[16];
  #pragma unroll
  for (int i = 0; i < 16; ++i) A[i] = sup[(size_t)i * 64 + lane];

  unsigned long long accept = 0;
  for (int c = 0; c < 256; c += 2) {
    // block boundary: resolve accept mask for block b = c/4 (only at even c, c%4==0)
    if ((c & 3) == 0) {
      int b = c >> 2;
      unsigned long long d = diag[(b << 6) + lane];
      unsigned long long nz = __ballot(d != 0ull);
      unsigned long long m = readlane64(keep, b);
      while (nz) {
        int p = __builtin_ctzll(nz); nz &= nz - 1;
        if ((m >> p) & 1ull) m &= ~readlane64(d, p);
      }
      accept = m;  // final m == accept mask (zero-diag rows never modify m)
    }
    // prefetch chunk c+1 into B (rows' words below their block are all zero)
    {
      int bb = (c + 1) >> 2;
      #pragma unroll
      for (int i = 0; i < 16; ++i) {
        unsigned long long v = 0ull;
        if (lane >= bb) v = sup[((size_t)(c + 1) * 16 + i) * 64 + lane];
        B[i] = v;
      }
    }
    // apply chunk c from A
    {
      int base = (c & 3) << 4;
      unsigned long long a0 = 0, a1 = 0, a2 = 0, a3 = 0;
      #pragma unroll
      for (int i = 0; i < 16; ++i) {
        unsigned long long sel = ((accept >> (base + i)) & 1ull) ? ~0ull : 0ull;
        unsigned long long v = A[i] & sel;
        if ((i & 3) == 0) a0 |= v; else if ((i & 3) == 1) a1 |= v;
        else if ((i & 3) == 2) a2 |= v; else a3 |= v;
      }
      keep &= ~((a0 | a1) | (a2 | a3));
    }
    // prefetch chunk c+2 into A
    if (c + 2 < 256) {
      int bb = (c + 2) >> 2;
      #pragma unroll
      for (int i = 0; i < 16; ++i) {
        unsigned long long v = 0ull;
        if (lane >= bb) v = sup[((size_t)(c + 2) * 16 + i) * 64 + lane];
        A[i] = v;
      }
    }
    // apply chunk c+1 from B
    {
      int base = ((c + 1) & 3) << 4;
      unsigned long long a0 = 0, a1 = 0, a2 = 0, a3 = 0;
      #pragma unroll
      for (int i = 0; i < 16; ++i) {
        unsigned long long sel = ((accept >> (base + i)) & 1ull) ? ~0ull : 0ull;
        unsigned long long v = B[i] & sel;
        if ((i & 3) == 0) a0 |= v; else if ((i & 3) == 1) a1 |= v;
        else if ((i & 3) == 2) a2 |= v; else a3 |= v;
      }
      keep &= ~((a0 | a1) | (a2 | a3));
    }
  }

  // ranks: exclusive prefix of popcounts across lanes
  int cnt = __builtin_popcountll(keep);
  int pfx = 0;
  for (int l = 0; l < 64; ++l) {
    int c = __shfl(cnt, l);
    if (l < lane) pfx += c;
  }
  __syncthreads();  // order zero-fill before row writes

  unsigned long long kk = keep;
  int local = 0;
  while (kk) {
    int b = __builtin_ctzll(kk);
    kk &= kk - 1;
    int rank = pfx + local; local++;
    if (rank < KPOST) {
      int i = lane * 64 + b;
      out[rank * 6 + 0] = x1a[i];
      out[rank * 6 + 1] = y1a[i];
      out[rank * 6 + 2] = x2a[i];
      out[rank * 6 + 3] = y2a[i];
      out[rank * 6 + 4] = vala[i];
      out[rank * 6 + 5] = (float)laba[i];
    }
  }
}

extern "C" void kernel_launch(void* const* d_in, const int* in_sizes, int n_in,
                              void* d_out, int out_size, void* d_ws, size_t ws_size,
                              hipStream_t stream) {
  const float* boxes = (const float*)d_in[0];
  const float* cls   = (const float*)d_in[1];
  float* out = (float*)d_out;
  char* ws = (char*)d_ws;

  unsigned long long* keys  = (unsigned long long*)(ws + OFF_KEYS);
  unsigned long long* cand  = (unsigned long long*)(ws + OFF_CAND);
  unsigned long long* cand2 = (unsigned long long*)(ws + OFF_CAND2);
  unsigned long long* sel   = (unsigned long long*)(ws + OFF_SEL);
  unsigned long long* skeys = (unsigned long long*)(ws + OFF_SKEYS);
  unsigned long long* sup   = (unsigned long long*)(ws + OFF_SUP);
  unsigned long long* vmask = (unsigned long long*)(ws + OFF_VMASK);
  unsigned long long* diag  = (unsigned long long*)(ws + OFF_DIAG);
  uint32_t* hist = (uint32_t*)(ws + OFF_HIST);
  NmsState* st = (NmsState*)(ws + OFF_STATE);
  float* x1a = (float*)(ws + OFF_ARR);
  float* y1a = x1a + KPRE;
  float* x2a = y1a + KPRE;
  float* y2a = x2a + KPRE;
  float* vala = y2a + KPRE;
  int*   laba = (int*)(vala + KPRE);

  k_zero<<<1, 256, 0, stream>>>(hist, st, vmask);
  k_score<<<1024, 256, 0, stream>>>(cls, keys, hist);
  k_scan<<<1, 64, 0, stream>>>(hist, st, 0);
  k_hist1<<<1024, 256, 0, stream>>>(keys, st, hist + 256);
  k_scan<<<1, 64, 0, stream>>>(hist + 256, st, 1);
  k_compact_hist2<<<1024, 256, 0, stream>>>(keys, st, hist + 512, cand);
  k_scan<<<1, 64, 0, stream>>>(hist + 512, st, 2);
  k_filter24<<<64, 256, 0, stream>>>(cand, st, cand2);
  k_pivot<<<1, 1024, 0, stream>>>(cand2, st);
  k_select<<<64, 256, 0, stream>>>(cand, st, sel);
  k_sortsel<<<1, 1024, 0, stream>>>(sel, st, skeys);
  k_gather<<<16, 256, 0, stream>>>(skeys, boxes, cls, x1a, y1a, x2a, y2a, vala, laba, vmask);
  k_supmat<<<dim3(64, 64), 64, 0, stream>>>(x1a, y1a, x2a, y2a, sup, diag);
  k_scan_nms<<<1, 64, 0, stream>>>(sup, diag, vmask, x1a, y1a, x2a, y2a, vala, laba, out);
}

// Round 3
// 659.569 us; speedup vs baseline: 1.5686x; 1.3921x over previous
//
#include <hip/hip_runtime.h>
#include <stdint.h>

#define NBOX 2000000
#define NCLS 10
#define KPRE 4096
#define KPOST 500
#define NSEG 64
#define SEGC 4096   // cand per-segment cap
#define SEG2 1024   // cand2 / sel per-segment cap
#define CSTR 16     // counter stride in u32 (one 64B cacheline per counter)

// ---- workspace layout (bytes) ----
#define OFF_KEYS   ((size_t)0)
#define OFF_CAND   ((size_t)16000000)                        // NSEG*SEGC*8 = 2 MB
#define OFF_CAND2  (OFF_CAND  + (size_t)NSEG * SEGC * 8)     // NSEG*SEG2*8 = 512 KB
#define OFF_SEL    (OFF_CAND2 + (size_t)NSEG * SEG2 * 8)     // 512 KB
#define OFF_SKEYS  (OFF_SEL   + (size_t)NSEG * SEG2 * 8)     // 32 KB
#define OFF_SUP    (OFF_SKEYS + (size_t)KPRE * 8)            // 2 MB
#define OFF_VMASK  (OFF_SUP   + (size_t)KPRE * 64 * 8)
#define OFF_HIST   (OFF_VMASK + (size_t)64 * 8)
#define OFF_CNTS   (OFF_HIST  + (size_t)768 * 4)             // 3*64 counters, 64B stride
#define OFF_STATE  (OFF_CNTS  + (size_t)3 * NSEG * CSTR * 4)
#define OFF_ARR    (OFF_STATE + (size_t)64)
#define OFF_DIAG   (OFF_ARR   + (size_t)KPRE * 24)

struct NmsState {
  uint32_t b1, b2, b3;
  uint32_t need1, need2, need3;
  uint32_t pad0, pad1, pad2, pad3;
  unsigned long long pivot;
};

__device__ __forceinline__ uint32_t f2ord(float f) {
  uint32_t b = __float_as_uint(f);
  return (b & 0x80000000u) ? ~b : (b | 0x80000000u);
}
__device__ __forceinline__ float ord2f(uint32_t ord) {
  uint32_t b = (ord & 0x80000000u) ? (ord ^ 0x80000000u) : ~ord;
  return __uint_as_float(b);
}

__device__ __forceinline__ unsigned long long readlane64(unsigned long long v, int l) {
  uint32_t lo = (uint32_t)__builtin_amdgcn_readlane((int)(uint32_t)v, l);
  uint32_t hi = (uint32_t)__builtin_amdgcn_readlane((int)(uint32_t)(v >> 32), l);
  return ((unsigned long long)hi << 32) | lo;
}

// wave-aggregated LDS histogram add (distinct-bin loop)
__device__ __forceinline__ void hist_add_wave(uint32_t* lh, uint32_t bin) {
  unsigned long long act = __ballot(1);
  int lane = threadIdx.x & 63;
  unsigned long long rem = act;
  while (rem) {
    int leader = __builtin_ctzll(rem);
    uint32_t lb = __shfl(bin, leader);
    unsigned long long same = __ballot(bin == lb) & act;
    if (lane == leader) atomicAdd(&lh[lb], (uint32_t)__builtin_popcountll(same));
    rem &= ~same;
  }
}

// wave-aggregated compaction into a segment: one atomic (distributed counter) per wave
__device__ __forceinline__ void wave_compact(bool take, unsigned long long key,
                                             uint32_t* counter, unsigned long long* buf,
                                             uint32_t cap) {
  unsigned long long mm = __ballot(take);
  if (take) {
    int lane = threadIdx.x & 63;
    unsigned long long lt = (lane == 0) ? 0ull : (~0ull >> (64 - lane));
    int rank = __builtin_popcountll(mm & lt);
    int leader = __builtin_ctzll(mm);
    uint32_t base = 0;
    if (rank == 0) base = atomicAdd(counter, (uint32_t)__builtin_popcountll(mm));
    base = __shfl(base, leader);
    uint32_t pos = base + (uint32_t)rank;
    if (pos < cap) buf[pos] = key;
  }
}

// ---------------- kernels ----------------

__global__ void k_zero(uint32_t* hist, NmsState* st, unsigned long long* vmask,
                       uint32_t* cnts) {
  int t = threadIdx.x;
  for (int i = t; i < 768; i += blockDim.x) hist[i] = 0;
  for (int i = t; i < 3 * NSEG * CSTR; i += blockDim.x) cnts[i] = 0;
  if (t < 64) vmask[t] = 0;
  if (t == 0) *st = NmsState{};
}

// scores (max over classes), masked, 64-bit keys, byte0 histogram
__global__ void k_score(const float* __restrict__ cls, unsigned long long* __restrict__ keys,
                        uint32_t* __restrict__ hist0) {
  __shared__ uint32_t lh[256];
  for (int i = threadIdx.x; i < 256; i += blockDim.x) lh[i] = 0;
  __syncthreads();
  const int nvec = NBOX / 4;
  for (int v = blockIdx.x * blockDim.x + threadIdx.x; v < nvec; v += gridDim.x * blockDim.x) {
    float4 m = reinterpret_cast<const float4*>(cls)[v];
    #pragma unroll
    for (int c = 1; c < NCLS; ++c) {
      float4 x = reinterpret_cast<const float4*>(cls + (size_t)c * NBOX)[v];
      m.x = fmaxf(m.x, x.x); m.y = fmaxf(m.y, x.y);
      m.z = fmaxf(m.z, x.z); m.w = fmaxf(m.w, x.w);
    }
    float s[4] = {m.x, m.y, m.z, m.w};
    #pragma unroll
    for (int q = 0; q < 4; ++q) {
      float ms = (s[q] >= 0.1f) ? s[q] : -1.0f;
      uint32_t u = ~f2ord(ms);
      keys[4 * v + q] = ((unsigned long long)u << 32) | (uint32_t)(4 * v + q);
      hist_add_wave(lh, u >> 24);
    }
  }
  __syncthreads();
  for (int i = threadIdx.x; i < 256; i += blockDim.x)
    if (lh[i]) atomicAdd(&hist0[i], lh[i]);
}

// scan a 256-bin histogram for the bucket containing the need-th smallest
__global__ void k_scan(const uint32_t* __restrict__ hist, NmsState* st, int stage) {
  if (threadIdx.x != 0 || blockIdx.x != 0) return;
  uint32_t need = (stage == 0) ? (uint32_t)KPRE : (stage == 1 ? st->need1 : st->need2);
  uint32_t cum = 0, b = 255;
  for (int i = 0; i < 256; ++i) {
    uint32_t c = hist[i];
    if (cum + c >= need) { b = (uint32_t)i; break; }
    cum += c;
  }
  uint32_t nd = need - cum;
  if (stage == 0)      { st->b1 = b; st->need1 = nd; }
  else if (stage == 1) { st->b2 = b; st->need2 = nd; }
  else                 { st->b3 = b; st->need3 = nd; }
}

// byte1 histogram among byte0==b1
__global__ void k_hist1(const unsigned long long* __restrict__ keys,
                        const NmsState* __restrict__ st, uint32_t* __restrict__ hist1) {
  __shared__ uint32_t lh[256];
  for (int i = threadIdx.x; i < 256; i += blockDim.x) lh[i] = 0;
  __syncthreads();
  uint32_t b1 = st->b1;
  for (int i = blockIdx.x * blockDim.x + threadIdx.x; i < NBOX; i += gridDim.x * blockDim.x) {
    uint32_t u = (uint32_t)(keys[i] >> 32);
    if ((u >> 24) == b1) hist_add_wave(lh, (u >> 16) & 0xffu);
  }
  __syncthreads();
  for (int i = threadIdx.x; i < 256; i += blockDim.x)
    if (lh[i]) atomicAdd(&hist1[i], lh[i]);
}

// compact all keys with top16 <= (b1,b2) into segment blockIdx&63; byte2 histogram
__global__ void k_compact_hist2(const unsigned long long* __restrict__ keys,
                                const NmsState* __restrict__ st, uint32_t* __restrict__ hist2,
                                unsigned long long* __restrict__ cand,
                                uint32_t* __restrict__ cntc) {
  __shared__ uint32_t lh[256];
  for (int i = threadIdx.x; i < 256; i += blockDim.x) lh[i] = 0;
  __syncthreads();
  uint32_t p16 = (st->b1 << 8) | st->b2;
  int seg = blockIdx.x & (NSEG - 1);
  uint32_t* ctr = cntc + seg * CSTR;
  unsigned long long* buf = cand + (size_t)seg * SEGC;
  for (int i = blockIdx.x * blockDim.x + threadIdx.x; i < NBOX; i += gridDim.x * blockDim.x) {
    unsigned long long key = keys[i];
    uint32_t u = (uint32_t)(key >> 32);
    uint32_t pref = u >> 16;
    bool take = (pref <= p16);
    wave_compact(take, key, ctr, buf, SEGC);
    if (take && pref == p16) hist_add_wave(lh, (u >> 8) & 0xffu);
  }
  __syncthreads();
  for (int i = threadIdx.x; i < 256; i += blockDim.x)
    if (lh[i]) atomicAdd(&hist2[i], lh[i]);
}

// filter segment blockIdx.x of cand with top24 == (b1,b2,b3) into cand2 segment
__global__ void k_filter24(const unsigned long long* __restrict__ cand,
                           const uint32_t* __restrict__ cntc,
                           const NmsState* __restrict__ st,
                           unsigned long long* __restrict__ cand2,
                           uint32_t* __restrict__ cnt2) {
  int seg = blockIdx.x;
  uint32_t n = cntc[seg * CSTR]; if (n > SEGC) n = SEGC;
  uint32_t p24 = (st->b1 << 16) | (st->b2 << 8) | st->b3;
  uint32_t* ctr = (uint32_t*)(cnt2 + seg * CSTR);
  unsigned long long* buf = cand2 + (size_t)seg * SEG2;
  const unsigned long long* src = cand + (size_t)seg * SEGC;
  for (uint32_t i = threadIdx.x; i < n; i += blockDim.x) {
    unsigned long long key = src[i];
    uint32_t u = (uint32_t)(key >> 32);
    wave_compact((u >> 8) == p24, key, ctr, buf, SEG2);
  }
}

__device__ void bitonic4096(unsigned long long* s) {
  for (int k = 2; k <= KPRE; k <<= 1)
    for (int j = k >> 1; j > 0; j >>= 1) {
      __syncthreads();
      for (int t = threadIdx.x; t < KPRE; t += blockDim.x) {
        int ixj = t ^ j;
        if (ixj > t) {
          bool up = ((t & k) == 0);
          unsigned long long a = s[t], b = s[ixj];
          if ((a > b) == up) { s[t] = b; s[ixj] = a; }
        }
      }
    }
  __syncthreads();
}

// gather segmented buffer into LDS (padded with ~0), n capped at KPRE
__device__ void gather_segs(const unsigned long long* __restrict__ src,
                            const uint32_t* __restrict__ cnts, int segcap,
                            unsigned long long* s, uint32_t* offs) {
  if (threadIdx.x == 0) {
    uint32_t o = 0;
    for (int g = 0; g < NSEG; ++g) {
      offs[g] = o;
      uint32_t c = cnts[g * CSTR]; if (c > (uint32_t)segcap) c = segcap;
      o += c;
    }
    offs[NSEG] = o;
  }
  __syncthreads();
  for (int t = threadIdx.x; t < KPRE; t += blockDim.x) s[t] = ~0ull;
  __syncthreads();
  for (int g = 0; g < NSEG; ++g) {
    uint32_t o = offs[g], c = offs[g + 1] - o;
    for (uint32_t i = threadIdx.x; i < c; i += blockDim.x)
      if (o + i < KPRE) s[o + i] = src[(size_t)g * segcap + i];
  }
  __syncthreads();
}

// sort pivot bucket, pivot = need3-th smallest
__global__ void k_pivot(const unsigned long long* __restrict__ cand2,
                        const uint32_t* __restrict__ cnt2, NmsState* st) {
  __shared__ unsigned long long s[KPRE];
  __shared__ uint32_t offs[NSEG + 1];
  gather_segs(cand2, cnt2, SEG2, s, offs);
  bitonic4096(s);
  if (threadIdx.x == 0) st->pivot = s[st->need3 - 1];
}

// select all keys <= pivot from cand segment blockIdx.x (exactly 4096 total)
__global__ void k_select(const unsigned long long* __restrict__ cand,
                         const uint32_t* __restrict__ cntc,
                         const NmsState* __restrict__ st,
                         unsigned long long* __restrict__ sel,
                         uint32_t* __restrict__ cnts) {
  int seg = blockIdx.x;
  uint32_t n = cntc[seg * CSTR]; if (n > SEGC) n = SEGC;
  unsigned long long piv = st->pivot;
  uint32_t* ctr = (uint32_t*)(cnts + seg * CSTR);
  unsigned long long* buf = sel + (size_t)seg * SEG2;
  const unsigned long long* src = cand + (size_t)seg * SEGC;
  for (uint32_t i = threadIdx.x; i < n; i += blockDim.x) {
    unsigned long long key = src[i];
    wave_compact(key <= piv, key, ctr, buf, SEG2);
  }
}

// sort the selected 4096 into final (score desc, idx asc) order
__global__ void k_sortsel(const unsigned long long* __restrict__ sel,
                          const uint32_t* __restrict__ cnts,
                          unsigned long long* __restrict__ skeys) {
  __shared__ unsigned long long s[KPRE];
  __shared__ uint32_t offs[NSEG + 1];
  gather_segs(sel, cnts, SEG2, s, offs);
  bitonic4096(s);
  for (int t = threadIdx.x; t < KPRE; t += blockDim.x) skeys[t] = s[t];
}

// gather boxes / labels / values for the sorted 4096
__global__ void k_gather(const unsigned long long* __restrict__ skeys,
                         const float* __restrict__ boxes, const float* __restrict__ cls,
                         float* __restrict__ x1a, float* __restrict__ y1a,
                         float* __restrict__ x2a, float* __restrict__ y2a,
                         float* __restrict__ vala, int* __restrict__ laba,
                         unsigned long long* __restrict__ vmask) {
  int t = blockIdx.x * blockDim.x + threadIdx.x;
  if (t >= KPRE) return;
  unsigned long long key = skeys[t];
  uint32_t idx = (uint32_t)key;
  if (idx >= NBOX) idx = 0;  // safety (only on pipeline failure)
  uint32_t u = (uint32_t)(key >> 32);
  float val = ord2f(~u);
  x1a[t] = boxes[idx];
  y1a[t] = boxes[(size_t)NBOX + idx];
  x2a[t] = boxes[(size_t)2 * NBOX + idx];
  y2a[t] = boxes[(size_t)3 * NBOX + idx];
  float best = cls[idx];
  int lab = 0;
  #pragma unroll
  for (int c = 1; c < NCLS; ++c) {
    float v = cls[(size_t)c * NBOX + idx];
    if (v > best) { best = v; lab = c; }
  }
  vala[t] = val;
  laba[t] = lab;
  if (val >= 0.1f) atomicOr(&vmask[t >> 6], 1ull << (t & 63));
}

// 4096x4096 suppression bit-matrix; also diagonal block words to dg[i]
__global__ void k_supmat(const float* __restrict__ x1a, const float* __restrict__ y1a,
                         const float* __restrict__ x2a, const float* __restrict__ y2a,
                         unsigned long long* __restrict__ sup,
                         unsigned long long* __restrict__ dg) {
#pragma clang fp contract(off)
  int bx = blockIdx.x, by = blockIdx.y;
  int t = threadIdx.x;  // 64 threads
  int i = by * 64 + t;
  if (bx < by) { sup[(size_t)i * 64 + bx] = 0ull; return; }
  __shared__ float sx1[64], sy1[64], sx2[64], sy2[64], sar[64];
  int j0 = bx * 64 + t;
  float cx1 = x1a[j0], cy1 = y1a[j0], cx2 = x2a[j0], cy2 = y2a[j0];
  sx1[t] = cx1; sy1[t] = cy1; sx2[t] = cx2; sy2[t] = cy2;
  sar[t] = fmaxf(cx2 - cx1, 0.0f) * fmaxf(cy2 - cy1, 0.0f);
  __syncthreads();
  float x1i = x1a[i], y1i = y1a[i], x2i = x2a[i], y2i = y2a[i];
  float ari = fmaxf(x2i - x1i, 0.0f) * fmaxf(y2i - y1i, 0.0f);
  unsigned long long w = 0ull;
  #pragma unroll 8
  for (int jj = 0; jj < 64; ++jj) {
    int j = bx * 64 + jj;
    float iw = fmaxf(fminf(x2i, sx2[jj]) - fmaxf(x1i, sx1[jj]), 0.0f);
    float ih = fmaxf(fminf(y2i, sy2[jj]) - fmaxf(y1i, sy1[jj]), 0.0f);
    float inter = iw * ih;
    float den = ((ari + sar[jj]) - inter) + 1e-8f;  // exact ref op order
    float iou = inter / den;
    if ((iou > 0.5f) && (j > i)) w |= (1ull << jj);
  }
  sup[(size_t)i * 64 + bx] = w;
  if (bx == by) dg[i] = w;
}

// single-wave greedy scan, block-resolved
__global__ void k_scan_nms(const unsigned long long* __restrict__ sup,
                           const unsigned long long* __restrict__ diag,
                           const unsigned long long* __restrict__ vmask,
                           const float* __restrict__ x1a, const float* __restrict__ y1a,
                           const float* __restrict__ x2a, const float* __restrict__ y2a,
                           const float* __restrict__ vala, const int* __restrict__ laba,
                           float* __restrict__ out) {
  int lane = threadIdx.x;  // 64 threads = 1 wave
  unsigned long long keep = vmask[lane];

  for (int t = lane; t < KPOST * 6; t += 64) out[t] = 0.0f;

  unsigned long long A[16], B[16];
  #pragma unroll
  for (int i = 0; i < 16; ++i) A[i] = sup[(size_t)i * 64 + lane];

  unsigned long long accept = 0;
  for (int c = 0; c < 256; c += 2) {
    if ((c & 3) == 0) {
      int b = c >> 2;
      unsigned long long d = diag[(b << 6) + lane];
      unsigned long long nz = __ballot(d != 0ull);
      unsigned long long m = readlane64(keep, b);
      while (nz) {
        int p = __builtin_ctzll(nz); nz &= nz - 1;
        if ((m >> p) & 1ull) m &= ~readlane64(d, p);
      }
      accept = m;
    }
    {
      int bb = (c + 1) >> 2;
      #pragma unroll
      for (int i = 0; i < 16; ++i) {
        unsigned long long v = 0ull;
        if (lane >= bb) v = sup[((size_t)(c + 1) * 16 + i) * 64 + lane];
        B[i] = v;
      }
    }
    {
      int base = (c & 3) << 4;
      unsigned long long a0 = 0, a1 = 0, a2 = 0, a3 = 0;
      #pragma unroll
      for (int i = 0; i < 16; ++i) {
        unsigned long long sel = ((accept >> (base + i)) & 1ull) ? ~0ull : 0ull;
        unsigned long long v = A[i] & sel;
        if ((i & 3) == 0) a0 |= v; else if ((i & 3) == 1) a1 |= v;
        else if ((i & 3) == 2) a2 |= v; else a3 |= v;
      }
      keep &= ~((a0 | a1) | (a2 | a3));
    }
    if (c + 2 < 256) {
      int bb = (c + 2) >> 2;
      #pragma unroll
      for (int i = 0; i < 16; ++i) {
        unsigned long long v = 0ull;
        if (lane >= bb) v = sup[((size_t)(c + 2) * 16 + i) * 64 + lane];
        A[i] = v;
      }
    }
    {
      int base = ((c + 1) & 3) << 4;
      unsigned long long a0 = 0, a1 = 0, a2 = 0, a3 = 0;
      #pragma unroll
      for (int i = 0; i < 16; ++i) {
        unsigned long long sel = ((accept >> (base + i)) & 1ull) ? ~0ull : 0ull;
        unsigned long long v = B[i] & sel;
        if ((i & 3) == 0) a0 |= v; else if ((i & 3) == 1) a1 |= v;
        else if ((i & 3) == 2) a2 |= v; else a3 |= v;
      }
      keep &= ~((a0 | a1) | (a2 | a3));
    }
  }

  int cnt = __builtin_popcountll(keep);
  int pfx = 0;
  for (int l = 0; l < 64; ++l) {
    int c = __shfl(cnt, l);
    if (l < lane) pfx += c;
  }
  __syncthreads();

  unsigned long long kk = keep;
  int local = 0;
  while (kk) {
    int b = __builtin_ctzll(kk);
    kk &= kk - 1;
    int rank = pfx + local; local++;
    if (rank < KPOST) {
      int i = lane * 64 + b;
      out[rank * 6 + 0] = x1a[i];
      out[rank * 6 + 1] = y1a[i];
      out[rank * 6 + 2] = x2a[i];
      out[rank * 6 + 3] = y2a[i];
      out[rank * 6 + 4] = vala[i];
      out[rank * 6 + 5] = (float)laba[i];
    }
  }
}

extern "C" void kernel_launch(void* const* d_in, const int* in_sizes, int n_in,
                              void* d_out, int out_size, void* d_ws, size_t ws_size,
                              hipStream_t stream) {
  const float* boxes = (const float*)d_in[0];
  const float* cls   = (const float*)d_in[1];
  float* out = (float*)d_out;
  char* ws = (char*)d_ws;

  unsigned long long* keys  = (unsigned long long*)(ws + OFF_KEYS);
  unsigned long long* cand  = (unsigned long long*)(ws + OFF_CAND);
  unsigned long long* cand2 = (unsigned long long*)(ws + OFF_CAND2);
  unsigned long long* sel   = (unsigned long long*)(ws + OFF_SEL);
  unsigned long long* skeys = (unsigned long long*)(ws + OFF_SKEYS);
  unsigned long long* sup   = (unsigned long long*)(ws + OFF_SUP);
  unsigned long long* vmask = (unsigned long long*)(ws + OFF_VMASK);
  unsigned long long* diag  = (unsigned long long*)(ws + OFF_DIAG);
  uint32_t* hist = (uint32_t*)(ws + OFF_HIST);
  uint32_t* cnts = (uint32_t*)(ws + OFF_CNTS);
  uint32_t* cntc  = cnts;                    // cand counters
  uint32_t* cnt2  = cnts + NSEG * CSTR;      // cand2 counters
  uint32_t* cnts3 = cnts + 2 * NSEG * CSTR;  // sel counters
  NmsState* st = (NmsState*)(ws + OFF_STATE);
  float* x1a = (float*)(ws + OFF_ARR);
  float* y1a = x1a + KPRE;
  float* x2a = y1a + KPRE;
  float* y2a = x2a + KPRE;
  float* vala = y2a + KPRE;
  int*   laba = (int*)(vala + KPRE);

  k_zero<<<1, 256, 0, stream>>>(hist, st, vmask, cnts);
  k_score<<<1024, 256, 0, stream>>>(cls, keys, hist);
  k_scan<<<1, 64, 0, stream>>>(hist, st, 0);
  k_hist1<<<1024, 256, 0, stream>>>(keys, st, hist + 256);
  k_scan<<<1, 64, 0, stream>>>(hist + 256, st, 1);
  k_compact_hist2<<<1024, 256, 0, stream>>>(keys, st, hist + 512, cand, cntc);
  k_scan<<<1, 64, 0, stream>>>(hist + 512, st, 2);
  k_filter24<<<NSEG, 256, 0, stream>>>(cand, cntc, st, cand2, cnt2);
  k_pivot<<<1, 1024, 0, stream>>>(cand2, cnt2, st);
  k_select<<<NSEG, 256, 0, stream>>>(cand, cntc, st, sel, cnts3);
  k_sortsel<<<1, 1024, 0, stream>>>(sel, cnts3, skeys);
  k_gather<<<16, 256, 0, stream>>>(skeys, boxes, cls, x1a, y1a, x2a, y2a, vala, laba, vmask);
  k_supmat<<<dim3(64, 64), 64, 0, stream>>>(x1a, y1a, x2a, y2a, sup, diag);
  k_scan_nms<<<1, 64, 0, stream>>>(sup, diag, vmask, x1a, y1a, x2a, y2a, vala, laba, out);
}

// Round 4
// 450.307 us; speedup vs baseline: 2.2975x; 1.4647x over previous
//
#include <hip/hip_runtime.h>
#include <stdint.h>

#define NBOX 2000000
#define NCLS 10
#define KPRE 4096
#define KPOST 500
#define NSEG 64
#define SEGC 4096   // cand per-segment cap
#define SEG2 1024   // cand2 / sel per-segment cap
#define PSEG 2048   // pairs per-segment cap
#define LCAP 24576  // LDS pair cache (96 KB)
#define CSTR 16     // counter stride in u32 (one 64B cacheline per counter)

// ---- workspace layout (bytes) ----
#define OFF_KEYS   ((size_t)0)
#define OFF_CAND   ((size_t)16000000)                        // NSEG*SEGC*8 = 2 MB
#define OFF_CAND2  (OFF_CAND  + (size_t)NSEG * SEGC * 8)
#define OFF_SEL    (OFF_CAND2 + (size_t)NSEG * SEG2 * 8)
#define OFF_SKEYS  (OFF_SEL   + (size_t)NSEG * SEG2 * 8)
#define OFF_PAIRS  (OFF_SKEYS + (size_t)KPRE * 8)            // NSEG*PSEG*4 = 512 KB
#define OFF_VMASK  (OFF_PAIRS + (size_t)NSEG * PSEG * 4)
#define OFF_HIST   (OFF_VMASK + (size_t)64 * 8)
#define OFF_CNTS   (OFF_HIST  + (size_t)768 * 4)             // 4*64 counters, 64B stride
#define OFF_STATE  (OFF_CNTS  + (size_t)4 * NSEG * CSTR * 4)
#define OFF_ARR    (OFF_STATE + (size_t)64)

struct NmsState {
  uint32_t b1, b2, b3;
  uint32_t need1, need2, need3;
  uint32_t pad0, pad1, pad2, pad3;
  unsigned long long pivot;
};

__device__ __forceinline__ uint32_t f2ord(float f) {
  uint32_t b = __float_as_uint(f);
  return (b & 0x80000000u) ? ~b : (b | 0x80000000u);
}
__device__ __forceinline__ float ord2f(uint32_t ord) {
  uint32_t b = (ord & 0x80000000u) ? (ord ^ 0x80000000u) : ~ord;
  return __uint_as_float(b);
}

// wave-aggregated compaction (u64 payload): one atomic per wave
__device__ __forceinline__ void wave_compact(bool take, unsigned long long key,
                                             uint32_t* counter, unsigned long long* buf,
                                             uint32_t cap) {
  unsigned long long mm = __ballot(take);
  if (take) {
    int lane = threadIdx.x & 63;
    unsigned long long lt = (lane == 0) ? 0ull : (~0ull >> (64 - lane));
    int rank = __builtin_popcountll(mm & lt);
    int leader = __builtin_ctzll(mm);
    uint32_t base = 0;
    if (rank == 0) base = atomicAdd(counter, (uint32_t)__builtin_popcountll(mm));
    base = __shfl(base, leader);
    uint32_t pos = base + (uint32_t)rank;
    if (pos < cap) buf[pos] = key;
  }
}

// wave-aggregated compaction (u32 payload)
__device__ __forceinline__ void wave_compact32(bool take, uint32_t key,
                                               uint32_t* counter, uint32_t* buf,
                                               uint32_t cap) {
  unsigned long long mm = __ballot(take);
  if (take) {
    int lane = threadIdx.x & 63;
    unsigned long long lt = (lane == 0) ? 0ull : (~0ull >> (64 - lane));
    int rank = __builtin_popcountll(mm & lt);
    int leader = __builtin_ctzll(mm);
    uint32_t base = 0;
    if (rank == 0) base = atomicAdd(counter, (uint32_t)__builtin_popcountll(mm));
    base = __shfl(base, leader);
    uint32_t pos = base + (uint32_t)rank;
    if (pos < cap) buf[pos] = key;
  }
}

// ---------------- kernels ----------------

__global__ void k_zero(uint32_t* hist, NmsState* st, unsigned long long* vmask,
                       uint32_t* cnts) {
  int t = threadIdx.x;
  for (int i = t; i < 768; i += blockDim.x) hist[i] = 0;
  for (int i = t; i < 4 * NSEG * CSTR; i += blockDim.x) cnts[i] = 0;
  if (t < 64) vmask[t] = 0;
  if (t == 0) *st = NmsState{};
}

// scores (max over classes), masked, 64-bit keys, byte0 histogram
__global__ void k_score(const float* __restrict__ cls, unsigned long long* __restrict__ keys,
                        uint32_t* __restrict__ hist0) {
  __shared__ uint32_t lh[256];
  for (int i = threadIdx.x; i < 256; i += blockDim.x) lh[i] = 0;
  __syncthreads();
  const int nvec = NBOX / 4;
  for (int v = blockIdx.x * blockDim.x + threadIdx.x; v < nvec; v += gridDim.x * blockDim.x) {
    float4 m = reinterpret_cast<const float4*>(cls)[v];
    #pragma unroll
    for (int c = 1; c < NCLS; ++c) {
      float4 x = reinterpret_cast<const float4*>(cls + (size_t)c * NBOX)[v];
      m.x = fmaxf(m.x, x.x); m.y = fmaxf(m.y, x.y);
      m.z = fmaxf(m.z, x.z); m.w = fmaxf(m.w, x.w);
    }
    float s[4] = {m.x, m.y, m.z, m.w};
    #pragma unroll
    for (int q = 0; q < 4; ++q) {
      float ms = (s[q] >= 0.1f) ? s[q] : -1.0f;
      uint32_t u = ~f2ord(ms);
      keys[4 * v + q] = ((unsigned long long)u << 32) | (uint32_t)(4 * v + q);
      atomicAdd(&lh[u >> 24], 1u);
    }
  }
  __syncthreads();
  for (int i = threadIdx.x; i < 256; i += blockDim.x)
    if (lh[i]) atomicAdd(&hist0[i], lh[i]);
}

// scan a 256-bin histogram for the bucket containing the need-th smallest
__global__ void k_scan(const uint32_t* __restrict__ hist, NmsState* st, int stage) {
  if (threadIdx.x != 0 || blockIdx.x != 0) return;
  uint32_t need = (stage == 0) ? (uint32_t)KPRE : (stage == 1 ? st->need1 : st->need2);
  uint32_t cum = 0, b = 255;
  for (int i = 0; i < 256; ++i) {
    uint32_t c = hist[i];
    if (cum + c >= need) { b = (uint32_t)i; break; }
    cum += c;
  }
  uint32_t nd = need - cum;
  if (stage == 0)      { st->b1 = b; st->need1 = nd; }
  else if (stage == 1) { st->b2 = b; st->need2 = nd; }
  else                 { st->b3 = b; st->need3 = nd; }
}

// byte1 histogram among byte0==b1
__global__ void k_hist1(const unsigned long long* __restrict__ keys,
                        const NmsState* __restrict__ st, uint32_t* __restrict__ hist1) {
  __shared__ uint32_t lh[256];
  for (int i = threadIdx.x; i < 256; i += blockDim.x) lh[i] = 0;
  __syncthreads();
  uint32_t b1 = st->b1;
  for (int i = blockIdx.x * blockDim.x + threadIdx.x; i < NBOX; i += gridDim.x * blockDim.x) {
    uint32_t u = (uint32_t)(keys[i] >> 32);
    if ((u >> 24) == b1) atomicAdd(&lh[(u >> 16) & 0xffu], 1u);
  }
  __syncthreads();
  for (int i = threadIdx.x; i < 256; i += blockDim.x)
    if (lh[i]) atomicAdd(&hist1[i], lh[i]);
}

// compact all keys with top16 <= (b1,b2) into segment blockIdx&63; byte2 histogram
__global__ void k_compact_hist2(const unsigned long long* __restrict__ keys,
                                const NmsState* __restrict__ st, uint32_t* __restrict__ hist2,
                                unsigned long long* __restrict__ cand,
                                uint32_t* __restrict__ cntc) {
  __shared__ uint32_t lh[256];
  for (int i = threadIdx.x; i < 256; i += blockDim.x) lh[i] = 0;
  __syncthreads();
  uint32_t p16 = (st->b1 << 8) | st->b2;
  int seg = blockIdx.x & (NSEG - 1);
  uint32_t* ctr = cntc + seg * CSTR;
  unsigned long long* buf = cand + (size_t)seg * SEGC;
  for (int i = blockIdx.x * blockDim.x + threadIdx.x; i < NBOX; i += gridDim.x * blockDim.x) {
    unsigned long long key = keys[i];
    uint32_t u = (uint32_t)(key >> 32);
    uint32_t pref = u >> 16;
    bool take = (pref <= p16);
    wave_compact(take, key, ctr, buf, SEGC);
    if (take && pref == p16) atomicAdd(&lh[(u >> 8) & 0xffu], 1u);
  }
  __syncthreads();
  for (int i = threadIdx.x; i < 256; i += blockDim.x)
    if (lh[i]) atomicAdd(&hist2[i], lh[i]);
}

// filter segment blockIdx.x of cand with top24 == (b1,b2,b3) into cand2 segment
__global__ void k_filter24(const unsigned long long* __restrict__ cand,
                           const uint32_t* __restrict__ cntc,
                           const NmsState* __restrict__ st,
                           unsigned long long* __restrict__ cand2,
                           uint32_t* __restrict__ cnt2) {
  int seg = blockIdx.x;
  uint32_t n = cntc[seg * CSTR]; if (n > SEGC) n = SEGC;
  uint32_t p24 = (st->b1 << 16) | (st->b2 << 8) | st->b3;
  uint32_t* ctr = (uint32_t*)(cnt2 + seg * CSTR);
  unsigned long long* buf = cand2 + (size_t)seg * SEG2;
  const unsigned long long* src = cand + (size_t)seg * SEGC;
  for (uint32_t i = threadIdx.x; i < n; i += blockDim.x) {
    unsigned long long key = src[i];
    uint32_t u = (uint32_t)(key >> 32);
    wave_compact((u >> 8) == p24, key, ctr, buf, SEG2);
  }
}

__device__ void bitonic4096(unsigned long long* s) {
  for (int k = 2; k <= KPRE; k <<= 1)
    for (int j = k >> 1; j > 0; j >>= 1) {
      __syncthreads();
      for (int t = threadIdx.x; t < KPRE; t += blockDim.x) {
        int ixj = t ^ j;
        if (ixj > t) {
          bool up = ((t & k) == 0);
          unsigned long long a = s[t], b = s[ixj];
          if ((a > b) == up) { s[t] = b; s[ixj] = a; }
        }
      }
    }
  __syncthreads();
}

// gather segmented buffer into LDS (padded with ~0), n capped at KPRE
__device__ void gather_segs(const unsigned long long* __restrict__ src,
                            const uint32_t* __restrict__ cnts, int segcap,
                            unsigned long long* s, uint32_t* offs) {
  if (threadIdx.x == 0) {
    uint32_t o = 0;
    for (int g = 0; g < NSEG; ++g) {
      offs[g] = o;
      uint32_t c = cnts[g * CSTR]; if (c > (uint32_t)segcap) c = segcap;
      o += c;
    }
    offs[NSEG] = o;
  }
  __syncthreads();
  for (int t = threadIdx.x; t < KPRE; t += blockDim.x) s[t] = ~0ull;
  __syncthreads();
  for (int g = 0; g < NSEG; ++g) {
    uint32_t o = offs[g], c = offs[g + 1] - o;
    for (uint32_t i = threadIdx.x; i < c; i += blockDim.x)
      if (o + i < KPRE) s[o + i] = src[(size_t)g * segcap + i];
  }
  __syncthreads();
}

// sort pivot bucket, pivot = need3-th smallest
__global__ void k_pivot(const unsigned long long* __restrict__ cand2,
                        const uint32_t* __restrict__ cnt2, NmsState* st) {
  __shared__ unsigned long long s[KPRE];
  __shared__ uint32_t offs[NSEG + 1];
  gather_segs(cand2, cnt2, SEG2, s, offs);
  bitonic4096(s);
  if (threadIdx.x == 0) st->pivot = s[st->need3 - 1];
}

// select all keys <= pivot from cand segment blockIdx.x (exactly 4096 total)
__global__ void k_select(const unsigned long long* __restrict__ cand,
                         const uint32_t* __restrict__ cntc,
                         const NmsState* __restrict__ st,
                         unsigned long long* __restrict__ sel,
                         uint32_t* __restrict__ cnts) {
  int seg = blockIdx.x;
  uint32_t n = cntc[seg * CSTR]; if (n > SEGC) n = SEGC;
  unsigned long long piv = st->pivot;
  uint32_t* ctr = (uint32_t*)(cnts + seg * CSTR);
  unsigned long long* buf = sel + (size_t)seg * SEG2;
  const unsigned long long* src = cand + (size_t)seg * SEGC;
  for (uint32_t i = threadIdx.x; i < n; i += blockDim.x) {
    unsigned long long key = src[i];
    wave_compact(key <= piv, key, ctr, buf, SEG2);
  }
}

// sort the selected 4096 into final (score desc, idx asc) order
__global__ void k_sortsel(const unsigned long long* __restrict__ sel,
                          const uint32_t* __restrict__ cnts,
                          unsigned long long* __restrict__ skeys) {
  __shared__ unsigned long long s[KPRE];
  __shared__ uint32_t offs[NSEG + 1];
  gather_segs(sel, cnts, SEG2, s, offs);
  bitonic4096(s);
  for (int t = threadIdx.x; t < KPRE; t += blockDim.x) skeys[t] = s[t];
}

// gather boxes / labels / values for the sorted 4096
__global__ void k_gather(const unsigned long long* __restrict__ skeys,
                         const float* __restrict__ boxes, const float* __restrict__ cls,
                         float* __restrict__ x1a, float* __restrict__ y1a,
                         float* __restrict__ x2a, float* __restrict__ y2a,
                         float* __restrict__ vala, int* __restrict__ laba,
                         unsigned long long* __restrict__ vmask) {
  int t = blockIdx.x * blockDim.x + threadIdx.x;
  if (t >= KPRE) return;
  unsigned long long key = skeys[t];
  uint32_t idx = (uint32_t)key;
  if (idx >= NBOX) idx = 0;  // safety (only on pipeline failure)
  uint32_t u = (uint32_t)(key >> 32);
  float val = ord2f(~u);
  x1a[t] = boxes[idx];
  y1a[t] = boxes[(size_t)NBOX + idx];
  x2a[t] = boxes[(size_t)2 * NBOX + idx];
  y2a[t] = boxes[(size_t)3 * NBOX + idx];
  float best = cls[idx];
  int lab = 0;
  #pragma unroll
  for (int c = 1; c < NCLS; ++c) {
    float v = cls[(size_t)c * NBOX + idx];
    if (v > best) { best = v; lab = c; }
  }
  vala[t] = val;
  laba[t] = lab;
  if (val >= 0.1f) atomicOr(&vmask[t >> 6], 1ull << (t & 63));
}

// sparse suppression pairs: (i<<16)|j for j>i, iou>0.5 (exact ref op order)
__global__ void k_pairs(const float* __restrict__ x1a, const float* __restrict__ y1a,
                        const float* __restrict__ x2a, const float* __restrict__ y2a,
                        uint32_t* __restrict__ pcnt, uint32_t* __restrict__ pairs) {
#pragma clang fp contract(off)
  int bx = blockIdx.x, by = blockIdx.y;
  if (bx < by) return;
  int t = threadIdx.x;  // 64 threads
  int i = by * 64 + t;
  __shared__ float sx1[64], sy1[64], sx2[64], sy2[64], sar[64];
  int j0 = bx * 64 + t;
  float cx1 = x1a[j0], cy1 = y1a[j0], cx2 = x2a[j0], cy2 = y2a[j0];
  sx1[t] = cx1; sy1[t] = cy1; sx2[t] = cx2; sy2[t] = cy2;
  sar[t] = fmaxf(cx2 - cx1, 0.0f) * fmaxf(cy2 - cy1, 0.0f);
  __syncthreads();
  float x1i = x1a[i], y1i = y1a[i], x2i = x2a[i], y2i = y2a[i];
  float ari = fmaxf(x2i - x1i, 0.0f) * fmaxf(y2i - y1i, 0.0f);
  unsigned long long w = 0ull;
  #pragma unroll 8
  for (int jj = 0; jj < 64; ++jj) {
    int j = bx * 64 + jj;
    float iw = fmaxf(fminf(x2i, sx2[jj]) - fmaxf(x1i, sx1[jj]), 0.0f);
    float ih = fmaxf(fminf(y2i, sy2[jj]) - fmaxf(y1i, sy1[jj]), 0.0f);
    float inter = iw * ih;
    float den = ((ari + sar[jj]) - inter) + 1e-8f;  // exact ref op order
    float iou = inter / den;
    if ((iou > 0.5f) && (j > i)) w |= (1ull << jj);
  }
  int seg = (by * 64 + bx) & (NSEG - 1);
  uint32_t* ctr = pcnt + seg * CSTR;
  uint32_t* buf = pairs + (size_t)seg * PSEG;
  while (__ballot(w != 0ull)) {
    bool tk = (w != 0ull);
    uint32_t pr = 0;
    if (tk) {
      int b = __builtin_ctzll(w); w &= w - 1;
      pr = ((uint32_t)i << 16) | (uint32_t)(bx * 64 + b);
    }
    wave_compact32(tk, pr, ctr, buf, PSEG);
  }
}

// Jacobi fixpoint of A[i] = V[i] & forall (j,i) in E: !A[j]  (== greedy NMS result;
// unique fixpoint by induction on index; depth-d nodes fixed after d iterations)
__global__ void __launch_bounds__(1024) k_fix(
    const uint32_t* __restrict__ pcnt, const uint32_t* __restrict__ pairs,
    const unsigned long long* __restrict__ vmask,
    const float* __restrict__ x1a, const float* __restrict__ y1a,
    const float* __restrict__ x2a, const float* __restrict__ y2a,
    const float* __restrict__ vala, const int* __restrict__ laba,
    float* __restrict__ out) {
  __shared__ uint32_t lp[LCAP];
  __shared__ uint32_t soff[NSEG + 1];
  __shared__ unsigned long long validm[64], accm[64];
  __shared__ uint32_t supp[128];
  __shared__ uint32_t chg, use_lds;
  int tid = threadIdx.x;

  for (int t = tid; t < KPOST * 6; t += 1024) out[t] = 0.0f;

  if (tid == 0) {
    uint32_t o = 0;
    for (int g = 0; g < NSEG; ++g) {
      soff[g] = o;
      uint32_t c = pcnt[g * CSTR]; if (c > (uint32_t)PSEG) c = PSEG;
      o += c;
    }
    soff[NSEG] = o;
    use_lds = (o <= (uint32_t)LCAP) ? 1u : 0u;
  }
  if (tid < 64) { validm[tid] = vmask[tid]; accm[tid] = vmask[tid]; }
  __syncthreads();
  uint32_t npair = soff[NSEG];
  if (use_lds) {
    for (int g = 0; g < NSEG; ++g) {
      uint32_t o = soff[g], c = soff[g + 1] - o;
      for (uint32_t p = tid; p < c; p += 1024) lp[o + p] = pairs[(size_t)g * PSEG + p];
    }
  }

  while (true) {
    __syncthreads();                       // protect chg read below from reset
    if (tid < 128) supp[tid] = 0;
    if (tid == 0) chg = 0;
    __syncthreads();
    if (use_lds) {
      for (uint32_t p = tid; p < npair; p += 1024) {
        uint32_t pr = lp[p];
        uint32_t i = pr >> 16, j = pr & 0xffffu;
        if ((accm[i >> 6] >> (i & 63)) & 1ull) atomicOr(&supp[j >> 5], 1u << (j & 31));
      }
    } else {
      for (int g = 0; g < NSEG; ++g) {
        uint32_t c = soff[g + 1] - soff[g];
        for (uint32_t p = tid; p < c; p += 1024) {
          uint32_t pr = pairs[(size_t)g * PSEG + p];
          uint32_t i = pr >> 16, j = pr & 0xffffu;
          if ((accm[i >> 6] >> (i & 63)) & 1ull) atomicOr(&supp[j >> 5], 1u << (j & 31));
        }
      }
    }
    __syncthreads();
    if (tid < 64) {
      unsigned long long s = ((unsigned long long)supp[2 * tid + 1] << 32) | supp[2 * tid];
      unsigned long long na = validm[tid] & ~s;
      if (na != accm[tid]) { accm[tid] = na; atomicOr(&chg, 1u); }
    }
    __syncthreads();
    if (chg == 0) break;
  }

  // wave 0: ranks via popcount prefix, then write surviving rows
  if (tid < 64) {
    unsigned long long keep = accm[tid];
    int cnt = __builtin_popcountll(keep);
    int pfx = 0;
    for (int l = 0; l < 64; ++l) {
      int c = __shfl(cnt, l);
      if (l < tid) pfx += c;
    }
    unsigned long long kk = keep;
    int local = 0;
    while (kk) {
      int b = __builtin_ctzll(kk);
      kk &= kk - 1;
      int rank = pfx + local; local++;
      if (rank < KPOST) {
        int i = tid * 64 + b;
        out[rank * 6 + 0] = x1a[i];
        out[rank * 6 + 1] = y1a[i];
        out[rank * 6 + 2] = x2a[i];
        out[rank * 6 + 3] = y2a[i];
        out[rank * 6 + 4] = vala[i];
        out[rank * 6 + 5] = (float)laba[i];
      }
    }
  }
}

extern "C" void kernel_launch(void* const* d_in, const int* in_sizes, int n_in,
                              void* d_out, int out_size, void* d_ws, size_t ws_size,
                              hipStream_t stream) {
  const float* boxes = (const float*)d_in[0];
  const float* cls   = (const float*)d_in[1];
  float* out = (float*)d_out;
  char* ws = (char*)d_ws;

  unsigned long long* keys  = (unsigned long long*)(ws + OFF_KEYS);
  unsigned long long* cand  = (unsigned long long*)(ws + OFF_CAND);
  unsigned long long* cand2 = (unsigned long long*)(ws + OFF_CAND2);
  unsigned long long* sel   = (unsigned long long*)(ws + OFF_SEL);
  unsigned long long* skeys = (unsigned long long*)(ws + OFF_SKEYS);
  uint32_t* pairs = (uint32_t*)(ws + OFF_PAIRS);
  unsigned long long* vmask = (unsigned long long*)(ws + OFF_VMASK);
  uint32_t* hist = (uint32_t*)(ws + OFF_HIST);
  uint32_t* cnts = (uint32_t*)(ws + OFF_CNTS);
  uint32_t* cntc  = cnts;                    // cand counters
  uint32_t* cnt2  = cnts + NSEG * CSTR;      // cand2 counters
  uint32_t* cnts3 = cnts + 2 * NSEG * CSTR;  // sel counters
  uint32_t* pcnt  = cnts + 3 * NSEG * CSTR;  // pair counters
  NmsState* st = (NmsState*)(ws + OFF_STATE);
  float* x1a = (float*)(ws + OFF_ARR);
  float* y1a = x1a + KPRE;
  float* x2a = y1a + KPRE;
  float* y2a = x2a + KPRE;
  float* vala = y2a + KPRE;
  int*   laba = (int*)(vala + KPRE);

  k_zero<<<1, 256, 0, stream>>>(hist, st, vmask, cnts);
  k_score<<<1024, 256, 0, stream>>>(cls, keys, hist);
  k_scan<<<1, 64, 0, stream>>>(hist, st, 0);
  k_hist1<<<1024, 256, 0, stream>>>(keys, st, hist + 256);
  k_scan<<<1, 64, 0, stream>>>(hist + 256, st, 1);
  k_compact_hist2<<<1024, 256, 0, stream>>>(keys, st, hist + 512, cand, cntc);
  k_scan<<<1, 64, 0, stream>>>(hist + 512, st, 2);
  k_filter24<<<NSEG, 256, 0, stream>>>(cand, cntc, st, cand2, cnt2);
  k_pivot<<<1, 1024, 0, stream>>>(cand2, cnt2, st);
  k_select<<<NSEG, 256, 0, stream>>>(cand, cntc, st, sel, cnts3);
  k_sortsel<<<1, 1024, 0, stream>>>(sel, cnts3, skeys);
  k_gather<<<16, 256, 0, stream>>>(skeys, boxes, cls, x1a, y1a, x2a, y2a, vala, laba, vmask);
  k_pairs<<<dim3(64, 64), 64, 0, stream>>>(x1a, y1a, x2a, y2a, pcnt, pairs);
  k_fix<<<1, 1024, 0, stream>>>(pcnt, pairs, vmask, x1a, y1a, x2a, y2a, vala, laba, out);
}

// Round 5
// 440.448 us; speedup vs baseline: 2.3489x; 1.0224x over previous
//
#include <hip/hip_runtime.h>
#include <stdint.h>

#define NBOX 2000000
#define NCLS 10
#define KPRE 4096
#define KPOST 500
#define NSEG 64
#define SEGC 4096   // cand per-segment cap
#define SEG2 1024   // cand2 / sel per-segment cap
#define PSEG 2048   // pairs per-segment cap
#define LCAP 24576  // LDS pair cache (96 KB)
#define CSTR 16     // counter stride in u32 (one 64B cacheline per counter)

// ---- workspace layout (bytes) ----
#define OFF_KEYS   ((size_t)0)
#define OFF_CAND   ((size_t)16000000)                        // NSEG*SEGC*8 = 2 MB
#define OFF_CAND2  (OFF_CAND  + (size_t)NSEG * SEGC * 8)
#define OFF_SEL    (OFF_CAND2 + (size_t)NSEG * SEG2 * 8)
#define OFF_SKEYS  (OFF_SEL   + (size_t)NSEG * SEG2 * 8)
#define OFF_PAIRS  (OFF_SKEYS + (size_t)KPRE * 8)            // NSEG*PSEG*4 = 512 KB
#define OFF_VMASK  (OFF_PAIRS + (size_t)NSEG * PSEG * 4)
#define OFF_HIST   (OFF_VMASK + (size_t)64 * 8)
#define OFF_CNTS   (OFF_HIST  + (size_t)768 * 4)             // 4*64 counters, 64B stride
#define OFF_STATE  (OFF_CNTS  + (size_t)4 * NSEG * CSTR * 4)
#define OFF_ARR    (OFF_STATE + (size_t)64)

struct NmsState {
  unsigned long long pivot;
};

__device__ __forceinline__ uint32_t f2ord(float f) {
  uint32_t b = __float_as_uint(f);
  return (b & 0x80000000u) ? ~b : (b | 0x80000000u);
}
__device__ __forceinline__ float ord2f(uint32_t ord) {
  uint32_t b = (ord & 0x80000000u) ? (ord ^ 0x80000000u) : ~ord;
  return __uint_as_float(b);
}

__device__ __forceinline__ unsigned long long shflx64(unsigned long long v, int mask) {
  union { unsigned long long u; int i[2]; } a; a.u = v;
  a.i[0] = __shfl_xor(a.i[0], mask, 64);
  a.i[1] = __shfl_xor(a.i[1], mask, 64);
  return a.u;
}
__device__ __forceinline__ unsigned long long bsel(unsigned long long a,
                                                   unsigned long long b, bool takemin) {
  return takemin ? (a < b ? a : b) : (a < b ? b : a);
}
__device__ __forceinline__ void cswap(unsigned long long& a, unsigned long long& b, bool up) {
  if ((a > b) == up) { unsigned long long t = a; a = b; b = t; }
}

// find bucket of the need-th smallest in a 256-bin histogram; *nd = rank within bucket
__device__ uint32_t scan256(const uint32_t* __restrict__ h, uint32_t need, uint32_t* nd) {
  uint32_t cum = 0;
  for (int i = 0; i < 256; ++i) {
    uint32_t c = h[i];
    if (cum + c >= need) { *nd = need - cum; return (uint32_t)i; }
    cum += c;
  }
  *nd = 1; return 255u;  // unreachable on valid input
}

// wave-aggregated compaction (u64 payload): one atomic per wave
__device__ __forceinline__ void wave_compact(bool take, unsigned long long key,
                                             uint32_t* counter, unsigned long long* buf,
                                             uint32_t cap) {
  unsigned long long mm = __ballot(take);
  if (take) {
    int lane = threadIdx.x & 63;
    unsigned long long lt = (lane == 0) ? 0ull : (~0ull >> (64 - lane));
    int rank = __builtin_popcountll(mm & lt);
    int leader = __builtin_ctzll(mm);
    uint32_t base = 0;
    if (rank == 0) base = atomicAdd(counter, (uint32_t)__builtin_popcountll(mm));
    base = __shfl(base, leader);
    uint32_t pos = base + (uint32_t)rank;
    if (pos < cap) buf[pos] = key;
  }
}

// wave-aggregated compaction (u32 payload)
__device__ __forceinline__ void wave_compact32(bool take, uint32_t key,
                                               uint32_t* counter, uint32_t* buf,
                                               uint32_t cap) {
  unsigned long long mm = __ballot(take);
  if (take) {
    int lane = threadIdx.x & 63;
    unsigned long long lt = (lane == 0) ? 0ull : (~0ull >> (64 - lane));
    int rank = __builtin_popcountll(mm & lt);
    int leader = __builtin_ctzll(mm);
    uint32_t base = 0;
    if (rank == 0) base = atomicAdd(counter, (uint32_t)__builtin_popcountll(mm));
    base = __shfl(base, leader);
    uint32_t pos = base + (uint32_t)rank;
    if (pos < cap) buf[pos] = key;
  }
}

// hybrid register/LDS bitonic sort of s[0..4095] ascending; blockDim.x == 1024.
// thread t owns elements [4t..4t+3]; j<4 in-thread, 4<=j<=128 shfl_xor, j>=256 LDS.
__device__ void sort4096(unsigned long long* s) {
  const int tid = threadIdx.x;
  const int g0 = tid << 2;
  unsigned long long e0 = s[g0], e1 = s[g0 + 1], e2 = s[g0 + 2], e3 = s[g0 + 3];
  for (int k = 2; k <= 4096; k <<= 1) {
    for (int j = k >> 1; j > 0; j >>= 1) {
      if (j >= 256) {
        s[g0] = e0; s[g0 + 1] = e1; s[g0 + 2] = e2; s[g0 + 3] = e3;
        __syncthreads();
        const int pb = g0 ^ j;
        unsigned long long o0 = s[pb], o1 = s[pb + 1], o2 = s[pb + 2], o3 = s[pb + 3];
        __syncthreads();
        bool sel = (((g0 & j) == 0) == ((g0 & k) == 0));
        e0 = bsel(e0, o0, sel); e1 = bsel(e1, o1, sel);
        e2 = bsel(e2, o2, sel); e3 = bsel(e3, o3, sel);
      } else if (j >= 4) {
        const int jj = j >> 2;
        bool sel = (((g0 & j) == 0) == ((g0 & k) == 0));
        unsigned long long o0 = shflx64(e0, jj), o1 = shflx64(e1, jj),
                           o2 = shflx64(e2, jj), o3 = shflx64(e3, jj);
        e0 = bsel(e0, o0, sel); e1 = bsel(e1, o1, sel);
        e2 = bsel(e2, o2, sel); e3 = bsel(e3, o3, sel);
      } else if (j == 2) {
        bool up = ((g0 & k) == 0);
        cswap(e0, e2, up); cswap(e1, e3, up);
      } else {
        bool up01 = ((g0 & k) == 0);
        bool up23 = (((g0 + 2) & k) == 0);
        cswap(e0, e1, up01); cswap(e2, e3, up23);
      }
    }
  }
  s[g0] = e0; s[g0 + 1] = e1; s[g0 + 2] = e2; s[g0 + 3] = e3;
  __syncthreads();
}

// ---------------- kernels ----------------

__global__ void k_zero(uint32_t* hist, NmsState* st, unsigned long long* vmask,
                       uint32_t* cnts) {
  int t = threadIdx.x;
  for (int i = t; i < 768; i += blockDim.x) hist[i] = 0;
  for (int i = t; i < 4 * NSEG * CSTR; i += blockDim.x) cnts[i] = 0;
  if (t < 64) vmask[t] = 0;
  if (t == 0) st->pivot = 0;
}

// scores (max over classes), masked, 64-bit keys, byte0 histogram
__global__ void k_score(const float* __restrict__ cls, unsigned long long* __restrict__ keys,
                        uint32_t* __restrict__ hist0) {
  __shared__ uint32_t lh[256];
  for (int i = threadIdx.x; i < 256; i += blockDim.x) lh[i] = 0;
  __syncthreads();
  const int nvec = NBOX / 4;
  for (int v = blockIdx.x * blockDim.x + threadIdx.x; v < nvec; v += gridDim.x * blockDim.x) {
    float4 m = reinterpret_cast<const float4*>(cls)[v];
    #pragma unroll
    for (int c = 1; c < NCLS; ++c) {
      float4 x = reinterpret_cast<const float4*>(cls + (size_t)c * NBOX)[v];
      m.x = fmaxf(m.x, x.x); m.y = fmaxf(m.y, x.y);
      m.z = fmaxf(m.z, x.z); m.w = fmaxf(m.w, x.w);
    }
    float s[4] = {m.x, m.y, m.z, m.w};
    #pragma unroll
    for (int q = 0; q < 4; ++q) {
      float ms = (s[q] >= 0.1f) ? s[q] : -1.0f;
      uint32_t u = ~f2ord(ms);
      keys[4 * v + q] = ((unsigned long long)u << 32) | (uint32_t)(4 * v + q);
      atomicAdd(&lh[u >> 24], 1u);
    }
  }
  __syncthreads();
  for (int i = threadIdx.x; i < 256; i += blockDim.x)
    if (lh[i]) atomicAdd(&hist0[i], lh[i]);
}

// byte1 histogram among byte0==b1 (b1 recomputed per block from hist0)
__global__ void k_hist1(const unsigned long long* __restrict__ keys,
                        const uint32_t* __restrict__ hist0, uint32_t* __restrict__ hist1) {
  __shared__ uint32_t lh[256];
  __shared__ uint32_t sb1;
  if (threadIdx.x == 0) { uint32_t nd; sb1 = scan256(hist0, KPRE, &nd); }
  for (int i = threadIdx.x; i < 256; i += blockDim.x) lh[i] = 0;
  __syncthreads();
  uint32_t b1 = sb1;
  for (int i = blockIdx.x * blockDim.x + threadIdx.x; i < NBOX; i += gridDim.x * blockDim.x) {
    uint32_t u = (uint32_t)(keys[i] >> 32);
    if ((u >> 24) == b1) atomicAdd(&lh[(u >> 16) & 0xffu], 1u);
  }
  __syncthreads();
  for (int i = threadIdx.x; i < 256; i += blockDim.x)
    if (lh[i]) atomicAdd(&hist1[i], lh[i]);
}

// compact all keys with top16 <= (b1,b2) into segment blockIdx&63; byte2 histogram
__global__ void k_compact_hist2(const unsigned long long* __restrict__ keys,
                                const uint32_t* __restrict__ hist, uint32_t* __restrict__ hist2,
                                unsigned long long* __restrict__ cand,
                                uint32_t* __restrict__ cntc) {
  __shared__ uint32_t lh[256];
  __shared__ uint32_t sp16;
  if (threadIdx.x == 0) {
    uint32_t nd1, nd2;
    uint32_t b1 = scan256(hist, KPRE, &nd1);
    uint32_t b2 = scan256(hist + 256, nd1, &nd2);
    sp16 = (b1 << 8) | b2;
  }
  for (int i = threadIdx.x; i < 256; i += blockDim.x) lh[i] = 0;
  __syncthreads();
  uint32_t p16 = sp16;
  int seg = blockIdx.x & (NSEG - 1);
  uint32_t* ctr = cntc + seg * CSTR;
  unsigned long long* buf = cand + (size_t)seg * SEGC;
  for (int i = blockIdx.x * blockDim.x + threadIdx.x; i < NBOX; i += gridDim.x * blockDim.x) {
    unsigned long long key = keys[i];
    uint32_t u = (uint32_t)(key >> 32);
    uint32_t pref = u >> 16;
    bool take = (pref <= p16);
    wave_compact(take, key, ctr, buf, SEGC);
    if (take && pref == p16) atomicAdd(&lh[(u >> 8) & 0xffu], 1u);
  }
  __syncthreads();
  for (int i = threadIdx.x; i < 256; i += blockDim.x)
    if (lh[i]) atomicAdd(&hist2[i], lh[i]);
}

// filter segment blockIdx.x of cand with top24 == (b1,b2,b3) into cand2 segment
__global__ void k_filter24(const unsigned long long* __restrict__ cand,
                           const uint32_t* __restrict__ cntc,
                           const uint32_t* __restrict__ hist,
                           unsigned long long* __restrict__ cand2,
                           uint32_t* __restrict__ cnt2) {
  __shared__ uint32_t sp24;
  if (threadIdx.x == 0) {
    uint32_t nd1, nd2, nd3;
    uint32_t b1 = scan256(hist, KPRE, &nd1);
    uint32_t b2 = scan256(hist + 256, nd1, &nd2);
    uint32_t b3 = scan256(hist + 512, nd2, &nd3);
    sp24 = (b1 << 16) | (b2 << 8) | b3;
  }
  __syncthreads();
  int seg = blockIdx.x;
  uint32_t n = cntc[seg * CSTR]; if (n > SEGC) n = SEGC;
  uint32_t p24 = sp24;
  uint32_t* ctr = cnt2 + seg * CSTR;
  unsigned long long* buf = cand2 + (size_t)seg * SEG2;
  const unsigned long long* src = cand + (size_t)seg * SEGC;
  for (uint32_t i = threadIdx.x; i < n; i += blockDim.x) {
    unsigned long long key = src[i];
    uint32_t u = (uint32_t)(key >> 32);
    wave_compact((u >> 8) == p24, key, ctr, buf, SEG2);
  }
}

// gather segmented buffer into LDS (padded with ~0), n capped at KPRE
__device__ void gather_segs(const unsigned long long* __restrict__ src,
                            const uint32_t* __restrict__ cnts, int segcap,
                            unsigned long long* s, uint32_t* offs) {
  if (threadIdx.x == 0) {
    uint32_t o = 0;
    for (int g = 0; g < NSEG; ++g) {
      offs[g] = o;
      uint32_t c = cnts[g * CSTR]; if (c > (uint32_t)segcap) c = segcap;
      o += c;
    }
    offs[NSEG] = o;
  }
  __syncthreads();
  for (int t = threadIdx.x; t < KPRE; t += blockDim.x) s[t] = ~0ull;
  __syncthreads();
  for (int g = 0; g < NSEG; ++g) {
    uint32_t o = offs[g], c = offs[g + 1] - o;
    for (uint32_t i = threadIdx.x; i < c; i += blockDim.x)
      if (o + i < KPRE) s[o + i] = src[(size_t)g * segcap + i];
  }
  __syncthreads();
}

// pivot = need3-th smallest of the 24-bit-exact bucket; fast single-wave path for n<=64
__global__ void __launch_bounds__(1024) k_pivot(const unsigned long long* __restrict__ cand2,
                        const uint32_t* __restrict__ cnt2,
                        const uint32_t* __restrict__ hist, NmsState* st) {
  __shared__ unsigned long long s[KPRE];
  __shared__ uint32_t offs[NSEG + 1];
  __shared__ uint32_t sneed3;
  if (threadIdx.x == 0) {
    uint32_t nd1, nd2, nd3;
    scan256(hist, KPRE, &nd1);
    scan256(hist + 256, nd1, &nd2);
    scan256(hist + 512, nd2, &nd3);
    sneed3 = nd3;
  }
  gather_segs(cand2, cnt2, SEG2, s, offs);
  uint32_t n = offs[NSEG], need3 = sneed3;
  if (n <= 64) {
    if (threadIdx.x < 64) {
      int lane = threadIdx.x;
      unsigned long long v = (lane < (int)n) ? s[lane] : ~0ull;
      for (int k = 2; k <= 64; k <<= 1)
        for (int j = k >> 1; j > 0; j >>= 1) {
          bool sel = (((lane & j) == 0) == ((lane & k) == 0));
          v = bsel(v, shflx64(v, j), sel);
        }
      if (lane == (int)need3 - 1) st->pivot = v;
    }
  } else {
    sort4096(s);
    if (threadIdx.x == 0) st->pivot = s[need3 - 1];
  }
}

// select all keys <= pivot from cand segment blockIdx.x (exactly 4096 total)
__global__ void k_select(const unsigned long long* __restrict__ cand,
                         const uint32_t* __restrict__ cntc,
                         const NmsState* __restrict__ st,
                         unsigned long long* __restrict__ sel,
                         uint32_t* __restrict__ cnts) {
  int seg = blockIdx.x;
  uint32_t n = cntc[seg * CSTR]; if (n > SEGC) n = SEGC;
  unsigned long long piv = st->pivot;
  uint32_t* ctr = cnts + seg * CSTR;
  unsigned long long* buf = sel + (size_t)seg * SEG2;
  const unsigned long long* src = cand + (size_t)seg * SEGC;
  for (uint32_t i = threadIdx.x; i < n; i += blockDim.x) {
    unsigned long long key = src[i];
    wave_compact(key <= piv, key, ctr, buf, SEG2);
  }
}

// sort the selected 4096 into final (score desc, idx asc) order
__global__ void __launch_bounds__(1024) k_sortsel(const unsigned long long* __restrict__ sel,
                          const uint32_t* __restrict__ cnts,
                          unsigned long long* __restrict__ skeys) {
  __shared__ unsigned long long s[KPRE];
  __shared__ uint32_t offs[NSEG + 1];
  gather_segs(sel, cnts, SEG2, s, offs);
  sort4096(s);
  for (int t = threadIdx.x; t < KPRE; t += 1024) skeys[t] = s[t];
}

// gather boxes / labels / values for the sorted 4096
__global__ void k_gather(const unsigned long long* __restrict__ skeys,
                         const float* __restrict__ boxes, const float* __restrict__ cls,
                         float* __restrict__ x1a, float* __restrict__ y1a,
                         float* __restrict__ x2a, float* __restrict__ y2a,
                         float* __restrict__ vala, int* __restrict__ laba,
                         unsigned long long* __restrict__ vmask) {
  int t = blockIdx.x * blockDim.x + threadIdx.x;
  if (t >= KPRE) return;
  unsigned long long key = skeys[t];
  uint32_t idx = (uint32_t)key;
  if (idx >= NBOX) idx = 0;  // safety (only on pipeline failure)
  uint32_t u = (uint32_t)(key >> 32);
  float val = ord2f(~u);
  x1a[t] = boxes[idx];
  y1a[t] = boxes[(size_t)NBOX + idx];
  x2a[t] = boxes[(size_t)2 * NBOX + idx];
  y2a[t] = boxes[(size_t)3 * NBOX + idx];
  float best = cls[idx];
  int lab = 0;
  #pragma unroll
  for (int c = 1; c < NCLS; ++c) {
    float v = cls[(size_t)c * NBOX + idx];
    if (v > best) { best = v; lab = c; }
  }
  vala[t] = val;
  laba[t] = lab;
  if (val >= 0.1f) atomicOr(&vmask[t >> 6], 1ull << (t & 63));
}

// sparse suppression pairs: (i<<16)|j for j>i, iou>0.5 (exact ref op order)
__global__ void k_pairs(const float* __restrict__ x1a, const float* __restrict__ y1a,
                        const float* __restrict__ x2a, const float* __restrict__ y2a,
                        uint32_t* __restrict__ pcnt, uint32_t* __restrict__ pairs) {
#pragma clang fp contract(off)
  int bx = blockIdx.x, by = blockIdx.y;
  if (bx < by) return;
  int t = threadIdx.x;  // 64 threads
  int i = by * 64 + t;
  __shared__ float sx1[64], sy1[64], sx2[64], sy2[64], sar[64];
  int j0 = bx * 64 + t;
  float cx1 = x1a[j0], cy1 = y1a[j0], cx2 = x2a[j0], cy2 = y2a[j0];
  sx1[t] = cx1; sy1[t] = cy1; sx2[t] = cx2; sy2[t] = cy2;
  sar[t] = fmaxf(cx2 - cx1, 0.0f) * fmaxf(cy2 - cy1, 0.0f);
  __syncthreads();
  float x1i = x1a[i], y1i = y1a[i], x2i = x2a[i], y2i = y2a[i];
  float ari = fmaxf(x2i - x1i, 0.0f) * fmaxf(y2i - y1i, 0.0f);
  unsigned long long w = 0ull;
  #pragma unroll 8
  for (int jj = 0; jj < 64; ++jj) {
    int j = bx * 64 + jj;
    float iw = fmaxf(fminf(x2i, sx2[jj]) - fmaxf(x1i, sx1[jj]), 0.0f);
    float ih = fmaxf(fminf(y2i, sy2[jj]) - fmaxf(y1i, sy1[jj]), 0.0f);
    float inter = iw * ih;
    float den = ((ari + sar[jj]) - inter) + 1e-8f;  // exact ref op order
    float iou = inter / den;
    if ((iou > 0.5f) && (j > i)) w |= (1ull << jj);
  }
  int seg = (by * 64 + bx) & (NSEG - 1);
  uint32_t* ctr = pcnt + seg * CSTR;
  uint32_t* buf = pairs + (size_t)seg * PSEG;
  while (__ballot(w != 0ull)) {
    bool tk = (w != 0ull);
    uint32_t pr = 0;
    if (tk) {
      int b = __builtin_ctzll(w); w &= w - 1;
      pr = ((uint32_t)i << 16) | (uint32_t)(bx * 64 + b);
    }
    wave_compact32(tk, pr, ctr, buf, PSEG);
  }
}

// Jacobi fixpoint of A[i] = V[i] & forall (j,i) in E: !A[j]  (== greedy NMS result)
__global__ void __launch_bounds__(1024) k_fix(
    const uint32_t* __restrict__ pcnt, const uint32_t* __restrict__ pairs,
    const unsigned long long* __restrict__ vmask,
    const float* __restrict__ x1a, const float* __restrict__ y1a,
    const float* __restrict__ x2a, const float* __restrict__ y2a,
    const float* __restrict__ vala, const int* __restrict__ laba,
    float* __restrict__ out) {
  __shared__ uint32_t lp[LCAP];
  __shared__ uint32_t soff[NSEG + 1];
  __shared__ unsigned long long validm[64], accm[64];
  __shared__ uint32_t supp[128];
  __shared__ uint32_t chg, use_lds;
  int tid = threadIdx.x;

  for (int t = tid; t < KPOST * 6; t += 1024) out[t] = 0.0f;

  if (tid == 0) {
    uint32_t o = 0;
    for (int g = 0; g < NSEG; ++g) {
      soff[g] = o;
      uint32_t c = pcnt[g * CSTR]; if (c > (uint32_t)PSEG) c = PSEG;
      o += c;
    }
    soff[NSEG] = o;
    use_lds = (o <= (uint32_t)LCAP) ? 1u : 0u;
  }
  if (tid < 64) { validm[tid] = vmask[tid]; accm[tid] = vmask[tid]; }
  __syncthreads();
  uint32_t npair = soff[NSEG];
  if (use_lds) {
    for (int g = 0; g < NSEG; ++g) {
      uint32_t o = soff[g], c = soff[g + 1] - o;
      for (uint32_t p = tid; p < c; p += 1024) lp[o + p] = pairs[(size_t)g * PSEG + p];
    }
  }

  while (true) {
    __syncthreads();
    if (tid < 128) supp[tid] = 0;
    if (tid == 0) chg = 0;
    __syncthreads();
    if (use_lds) {
      for (uint32_t p = tid; p < npair; p += 1024) {
        uint32_t pr = lp[p];
        uint32_t i = pr >> 16, j = pr & 0xffffu;
        if ((accm[i >> 6] >> (i & 63)) & 1ull) atomicOr(&supp[j >> 5], 1u << (j & 31));
      }
    } else {
      for (int g = 0; g < NSEG; ++g) {
        uint32_t c = soff[g + 1] - soff[g];
        for (uint32_t p = tid; p < c; p += 1024) {
          uint32_t pr = pairs[(size_t)g * PSEG + p];
          uint32_t i = pr >> 16, j = pr & 0xffffu;
          if ((accm[i >> 6] >> (i & 63)) & 1ull) atomicOr(&supp[j >> 5], 1u << (j & 31));
        }
      }
    }
    __syncthreads();
    if (tid < 64) {
      unsigned long long s = ((unsigned long long)supp[2 * tid + 1] << 32) | supp[2 * tid];
      unsigned long long na = validm[tid] & ~s;
      if (na != accm[tid]) { accm[tid] = na; atomicOr(&chg, 1u); }
    }
    __syncthreads();
    if (chg == 0) break;
  }

  if (tid < 64) {
    unsigned long long keep = accm[tid];
    int cnt = __builtin_popcountll(keep);
    int pfx = 0;
    for (int l = 0; l < 64; ++l) {
      int c = __shfl(cnt, l);
      if (l < tid) pfx += c;
    }
    unsigned long long kk = keep;
    int local = 0;
    while (kk) {
      int b = __builtin_ctzll(kk);
      kk &= kk - 1;
      int rank = pfx + local; local++;
      if (rank < KPOST) {
        int i = tid * 64 + b;
        out[rank * 6 + 0] = x1a[i];
        out[rank * 6 + 1] = y1a[i];
        out[rank * 6 + 2] = x2a[i];
        out[rank * 6 + 3] = y2a[i];
        out[rank * 6 + 4] = vala[i];
        out[rank * 6 + 5] = (float)laba[i];
      }
    }
  }
}

extern "C" void kernel_launch(void* const* d_in, const int* in_sizes, int n_in,
                              void* d_out, int out_size, void* d_ws, size_t ws_size,
                              hipStream_t stream) {
  const float* boxes = (const float*)d_in[0];
  const float* cls   = (const float*)d_in[1];
  float* out = (float*)d_out;
  char* ws = (char*)d_ws;

  unsigned long long* keys  = (unsigned long long*)(ws + OFF_KEYS);
  unsigned long long* cand  = (unsigned long long*)(ws + OFF_CAND);
  unsigned long long* cand2 = (unsigned long long*)(ws + OFF_CAND2);
  unsigned long long* sel   = (unsigned long long*)(ws + OFF_SEL);
  unsigned long long* skeys = (unsigned long long*)(ws + OFF_SKEYS);
  uint32_t* pairs = (uint32_t*)(ws + OFF_PAIRS);
  unsigned long long* vmask = (unsigned long long*)(ws + OFF_VMASK);
  uint32_t* hist = (uint32_t*)(ws + OFF_HIST);
  uint32_t* cnts = (uint32_t*)(ws + OFF_CNTS);
  uint32_t* cntc  = cnts;                    // cand counters
  uint32_t* cnt2  = cnts + NSEG * CSTR;      // cand2 counters
  uint32_t* cnts3 = cnts + 2 * NSEG * CSTR;  // sel counters
  uint32_t* pcnt  = cnts + 3 * NSEG * CSTR;  // pair counters
  NmsState* st = (NmsState*)(ws + OFF_STATE);
  float* x1a = (float*)(ws + OFF_ARR);
  float* y1a = x1a + KPRE;
  float* x2a = y1a + KPRE;
  float* y2a = x2a + KPRE;
  float* vala = y2a + KPRE;
  int*   laba = (int*)(vala + KPRE);

  k_zero<<<1, 256, 0, stream>>>(hist, st, vmask, cnts);
  k_score<<<1024, 256, 0, stream>>>(cls, keys, hist);
  k_hist1<<<1024, 256, 0, stream>>>(keys, hist, hist + 256);
  k_compact_hist2<<<1024, 256, 0, stream>>>(keys, hist, hist + 512, cand, cntc);
  k_filter24<<<NSEG, 256, 0, stream>>>(cand, cntc, hist, cand2, cnt2);
  k_pivot<<<1, 1024, 0, stream>>>(cand2, cnt2, hist, st);
  k_select<<<NSEG, 256, 0, stream>>>(cand, cntc, st, sel, cnts3);
  k_sortsel<<<1, 1024, 0, stream>>>(sel, cnts3, skeys);
  k_gather<<<16, 256, 0, stream>>>(skeys, boxes, cls, x1a, y1a, x2a, y2a, vala, laba, vmask);
  k_pairs<<<dim3(64, 64), 64, 0, stream>>>(x1a, y1a, x2a, y2a, pcnt, pairs);
  k_fix<<<1, 1024, 0, stream>>>(pcnt, pairs, vmask, x1a, y1a, x2a, y2a, vala, laba, out);
}